// Round 7
// baseline (725.008 us; speedup 1.0000x reference)
//
#include <hip/hip_runtime.h>
#include <hip/hip_bf16.h>

#define N_NODES 64000
#define BN_EPS 1e-5f
#define NBL 512      // radix blocks per type
#define NBKT 250     // coarse buckets = N_NODES / 256

typedef __attribute__((ext_vector_type(8))) short short8v;   // 8 bf16 (4 VGPRs)
typedef __attribute__((ext_vector_type(4))) float f32x4;

static inline int cdiv(long long a, int b) { return (int)((a + b - 1) / b); }

__device__ inline float bf2f(unsigned short u) {
  union { unsigned int i; float f; } v; v.i = ((unsigned int)u) << 16; return v.f;
}
__device__ inline unsigned short f2bf(float f) {
  __hip_bfloat16 h = __float2bfloat16(f);
  return *reinterpret_cast<unsigned short*>(&h);
}

// ================= atomic-free CSR build (two-level radix) =================
__global__ void r1_hist_kernel(const int* __restrict__ k0, const int* __restrict__ k1,
                               const int* __restrict__ k2, int E0, int E1, int E2,
                               int* __restrict__ Hist) {
  int t = blockIdx.x / NBL, blk = blockIdx.x - t * NBL;
  const int* key = t == 0 ? k0 : (t == 1 ? k1 : k2);
  int E = t == 0 ? E0 : (t == 1 ? E1 : E2);
  __shared__ int h[256];
  h[threadIdx.x] = 0;
  __syncthreads();
  int ch = (E + NBL - 1) / NBL;
  int lo = blk * ch, hi = min(lo + ch, E);
  for (int i = lo + threadIdx.x; i < hi; i += 256) atomicAdd(&h[key[i] >> 8], 1);
  __syncthreads();
  Hist[(t * NBL + blk) * 256 + threadIdx.x] = h[threadIdx.x];
}

__global__ void r2_scan_kernel(int* __restrict__ Hist, int* __restrict__ bbase,
                               int E0, int E1, int E2) {
  int t = blockIdx.x;
  int bin = threadIdx.x;
  int* H = Hist + (size_t)t * NBL * 256;
  int total = 0;
  for (int blk = 0; blk < NBL; ++blk) total += H[blk * 256 + bin];
  __shared__ int s[256];
  s[bin] = total;
  __syncthreads();
  for (int o = 1; o < 256; o <<= 1) {
    int a = (bin >= o) ? s[bin - o] : 0;
    __syncthreads();
    s[bin] += a;
    __syncthreads();
  }
  int base = s[bin] - total;
  if (bin <= NBKT) bbase[t * (NBKT + 1) + bin] = base;
  int run = base;
  for (int blk = 0; blk < NBL; ++blk) {
    int v = H[blk * 256 + bin];
    H[blk * 256 + bin] = run;
    run += v;
  }
}

__global__ void r3_scatter_kernel(const int* __restrict__ d0, const int* __restrict__ d1,
                                  const int* __restrict__ d2, const int* __restrict__ s0,
                                  const int* __restrict__ s1, const int* __restrict__ s2,
                                  int E0, int E1, int E2, const int* __restrict__ Hist,
                                  unsigned int* __restrict__ tmp) {
  int t = blockIdx.x / NBL, blk = blockIdx.x - t * NBL;
  const int* dst = t == 0 ? d0 : (t == 1 ? d1 : d2);
  const int* src = t == 0 ? s0 : (t == 1 ? s1 : s2);
  int E = t == 0 ? E0 : (t == 1 ? E1 : E2);
  unsigned int* tp = tmp + (t == 0 ? 0 : (t == 1 ? E0 : E0 + E1));
  __shared__ int off[256];
  off[threadIdx.x] = Hist[(t * NBL + blk) * 256 + threadIdx.x];
  __syncthreads();
  int ch = (E + NBL - 1) / NBL;
  int lo = blk * ch, hi = min(lo + ch, E);
  for (int i = lo + threadIdx.x; i < hi; i += 256) {
    int d = dst[i];
    int p = atomicAdd(&off[d >> 8], 1);
    tp[p] = ((unsigned)(d & 255) << 16) | (unsigned)src[i];
  }
}

__global__ void r4_bucket_kernel(const unsigned int* __restrict__ tmp,
                                 const int* __restrict__ bbase, int E0, int E1, int E2,
                                 unsigned short* __restrict__ es, int* __restrict__ row_ptr,
                                 int* __restrict__ cnt) {
  int t = blockIdx.x / NBKT, b = blockIdx.x - t * NBKT;
  const int* bb = bbase + t * (NBKT + 1);
  int teo = (t == 0 ? 0 : (t == 1 ? E0 : E0 + E1));
  int E = t == 0 ? E0 : (t == 1 ? E1 : E2);
  const unsigned int* tp = tmp + teo;
  unsigned short* esp = es + teo;
  int lo = bb[b], hi = bb[b + 1];
  __shared__ int c[256], s[256];
  c[threadIdx.x] = 0;
  __syncthreads();
  for (int i = lo + threadIdx.x; i < hi; i += 256) atomicAdd(&c[tp[i] >> 16], 1);
  __syncthreads();
  int v = c[threadIdx.x];
  s[threadIdx.x] = v;
  __syncthreads();
  for (int o = 1; o < 256; o <<= 1) {
    int a = (threadIdx.x >= o) ? s[threadIdx.x - o] : 0;
    __syncthreads();
    s[threadIdx.x] += a;
    __syncthreads();
  }
  int excl = s[threadIdx.x] - v;
  int node = b * 256 + threadIdx.x;
  cnt[(2 * t + 1) * N_NODES + node] = v;
  row_ptr[t * (N_NODES + 1) + node] = lo + excl;
  if (b == NBKT - 1 && threadIdx.x == 255) row_ptr[t * (N_NODES + 1) + N_NODES] = E;
  __syncthreads();
  s[threadIdx.x] = lo + excl;
  __syncthreads();
  for (int i = lo + threadIdx.x; i < hi; i += 256) {
    unsigned int w = tp[i];
    int p = atomicAdd(&s[w >> 16], 1);
    esp[p] = (unsigned short)(w & 0xFFFF);
  }
}

__global__ void r3b_scatter_kernel(const int* __restrict__ s0, const int* __restrict__ s1,
                                   const int* __restrict__ s2, int E0, int E1, int E2,
                                   const int* __restrict__ Hist, unsigned char* __restrict__ tmp8) {
  int t = blockIdx.x / NBL, blk = blockIdx.x - t * NBL;
  const int* src = t == 0 ? s0 : (t == 1 ? s1 : s2);
  int E = t == 0 ? E0 : (t == 1 ? E1 : E2);
  unsigned char* tp = tmp8 + (t == 0 ? 0 : (t == 1 ? E0 : E0 + E1));
  __shared__ int off[256];
  off[threadIdx.x] = Hist[(t * NBL + blk) * 256 + threadIdx.x];
  __syncthreads();
  int ch = (E + NBL - 1) / NBL;
  int lo = blk * ch, hi = min(lo + ch, E);
  for (int i = lo + threadIdx.x; i < hi; i += 256) {
    int sv = src[i];
    int p = atomicAdd(&off[sv >> 8], 1);
    tp[p] = (unsigned char)(sv & 255);
  }
}

__global__ void r4b_bucket_kernel(const unsigned char* __restrict__ tmp8,
                                  const int* __restrict__ bbase, int E0, int E1, int E2,
                                  int* __restrict__ cnt) {
  int t = blockIdx.x / NBKT, b = blockIdx.x - t * NBKT;
  const int* bb = bbase + t * (NBKT + 1);
  const unsigned char* tp = tmp8 + (t == 0 ? 0 : (t == 1 ? E0 : E0 + E1));
  int lo = bb[b], hi = bb[b + 1];
  __shared__ int c[256];
  c[threadIdx.x] = 0;
  __syncthreads();
  for (int i = lo + threadIdx.x; i < hi; i += 256) atomicAdd(&c[tp[i]], 1);
  __syncthreads();
  int node = b * 256 + threadIdx.x;
  cnt[(2 * t) * N_NODES + node] = c[threadIdx.x];
}

__global__ void rsqrt_inplace_kernel(void* buf, int n) {
  int i = blockIdx.x * blockDim.x + threadIdx.x;
  if (i < n) {
    int c = ((const int*)buf)[i];
    ((float*)buf)[i] = rsqrtf(fmaxf((float)c, 1.0f));
  }
}

// ---- f32 [N][64] -> bf16 col-blocked [2][N][32] ----
__global__ void f32_to_bf16_blk_kernel(const float* __restrict__ in,
                                       unsigned short* __restrict__ out) {
  int i4 = blockIdx.x * blockDim.x + threadIdx.x;   // over N*64/4
  if (i4 >= N_NODES * 16) return;
  int n = i4 >> 4, c4 = i4 & 15;
  float4 v = ((const float4*)in)[i4];
  int cb = c4 >> 3, cc = (c4 & 7) * 4;
  ushort4 o;
  o.x = f2bf(v.x); o.y = f2bf(v.y); o.z = f2bf(v.z); o.w = f2bf(v.w);
  *(ushort4*)&out[((size_t)cb * N_NODES + n) * 32 + cc] = o;
}

__global__ void pack_w_kernel(const float* __restrict__ W, unsigned short* __restrict__ Bp,
                              int Ksrc, int NOUT, int k_off, int NB) {
  int idx = blockIdx.x * blockDim.x + threadIdx.x;
  if (idx >= Ksrc * NOUT) return;
  int kl = idx / NOUT, n = idx - kl * NOUT;
  int k = k_off + kl;
  int kb = k >> 5, nb = n >> 4;
  int lane = (((k >> 3) & 3) << 4) | (n & 15);
  int e = k & 7;
  Bp[(((kb * NB) + nb) * 64 + lane) * 8 + e] = f2bf(W[idx]);
}

__global__ void bias_sum_kernel(const float* a, const float* b, const float* c,
                                float* o, int n) {
  int i = blockIdx.x * blockDim.x + threadIdx.x;
  if (i < n) o[i] = a[i] + b[i] + c[i];
}

// ---- col-blocked pull aggregation; slice (cb) is slow-varying in grid ----
// hb: [NCB][N][32]; wave = (cb, type, node); 2 half-waves process 2 edges in parallel
template<int NCB, int D, int STR>
__global__ __launch_bounds__(256) void gather_blk_kernel(
    const unsigned short* __restrict__ hb, const int* __restrict__ row_ptr_base,
    const unsigned short* __restrict__ es_base, const float* __restrict__ rs,
    unsigned short* __restrict__ out, int E0, int E01) {
  constexpr int BPP = 3 * N_NODES / 4;  // 256-thread blocks per slice phase
  int cb = blockIdx.x / BPP;
  int rblk = blockIdx.x - cb * BPP;
  int gwid = rblk * 4 + (threadIdx.x >> 6);
  int lane = threadIdx.x & 63;
  int t = (gwid >= N_NODES) + (gwid >= 2 * N_NODES);
  int node = gwid - t * N_NODES;
  int eoff = t == 0 ? 0 : (t == 1 ? E0 : E01);
  const int* row_ptr = row_ptr_base + t * (N_NODES + 1);
  const unsigned short* es = es_base + eoff;
  const float* rs_out = rs + (2 * t) * N_NODES;
  const float* rs_in = rs + (2 * t + 1) * N_NODES;
  const unsigned short* hs = hb + (size_t)cb * N_NODES * 32;
  int slot = lane >> 5, c = lane & 31;
  int lo = row_ptr[node], hi = row_ptr[node + 1];
  float acc = 0.f;
  int e = lo + slot;
  for (; e + 2 < hi; e += 4) {
    int s0 = __builtin_nontemporal_load(&es[e]);
    int s1 = __builtin_nontemporal_load(&es[e + 2]);
    acc += rs_out[s0] * bf2f(hs[s0 * 32 + c]) + rs_out[s1] * bf2f(hs[s1 * 32 + c]);
  }
  if (e < hi) {
    int s0 = __builtin_nontemporal_load(&es[e]);
    acc += rs_out[s0] * bf2f(hs[s0 * 32 + c]);
  }
  acc += __shfl_xor(acc, 32);
  if (slot == 0) {
    unsigned short v = f2bf(acc * rs_in[node]);
    __builtin_nontemporal_store(v, &out[(size_t)node * STR + t * D + cb * 32 + c]);
  }
}

// ---- MFMA GEMM with optional fused column-stats (sum, sumsq) epilogue ----
template<int K, int NOUT, int OUT_BF16, int STATS>
__global__ void gemm_kernel(const unsigned short* __restrict__ A,
                            const unsigned short* __restrict__ Bp,
                            const float* __restrict__ bias, void* __restrict__ outp,
                            float* __restrict__ stats) {
  constexpr int NB = NOUT / 16;
  constexpr int KB = K / 32;
  __shared__ float ls[STATS ? NOUT : 1], lq[STATS ? NOUT : 1];
  if (STATS) {
    for (int i = threadIdx.x; i < NOUT; i += blockDim.x) { ls[i] = 0.f; lq[i] = 0.f; }
    __syncthreads();
  }
  int wave = (blockIdx.x * blockDim.x + threadIdx.x) >> 6;
  int lane = threadIdx.x & 63;
  int row0 = wave * 16;
  int arow = row0 + (lane & 15);
  int kgrp = lane >> 4;
  f32x4 acc[NB];
#pragma unroll
  for (int i = 0; i < NB; ++i) acc[i] = (f32x4){0.f, 0.f, 0.f, 0.f};
  const short8v* ap = (const short8v*)(A + (long long)arow * K + kgrp * 8);
  const short8v* bp = (const short8v*)Bp;
#pragma unroll
  for (int kb = 0; kb < KB; ++kb) {
    short8v a = ap[kb * 4];
#pragma unroll
    for (int nb = 0; nb < NB; ++nb) {
      short8v b = bp[(kb * NB + nb) * 64 + lane];
      acc[nb] = __builtin_amdgcn_mfma_f32_16x16x32_bf16(a, b, acc[nb], 0, 0, 0);
    }
  }
  int r0 = (lane >> 4) * 4;
  int coll = lane & 15;
#pragma unroll
  for (int nb = 0; nb < NB; ++nb) {
    int col = nb * 16 + coll;
    float bv = bias[col];
    float s = 0.f, q = 0.f;
#pragma unroll
    for (int r = 0; r < 4; ++r) {
      long long row = row0 + r0 + r;
      float v = acc[nb][r] + bv;
      if (OUT_BF16) ((unsigned short*)outp)[row * NOUT + col] = f2bf(v);
      else ((float*)outp)[row * NOUT + col] = v;
      if (STATS) { s += v; q += v * v; }
    }
    if (STATS) {
      s += __shfl_xor(s, 16); q += __shfl_xor(q, 16);
      s += __shfl_xor(s, 32); q += __shfl_xor(q, 32);
      if (kgrp == 0) { atomicAdd(&ls[col], s); atomicAdd(&lq[col], q); }
    }
  }
  if (STATS) {
    __syncthreads();
    if (threadIdx.x < NOUT) {
      atomicAdd(&stats[threadIdx.x], ls[threadIdx.x]);
      atomicAdd(&stats[NOUT + threadIdx.x], lq[threadIdx.x]);
    }
  }
}

// ---- FC GEMM, fused BN->ReLU->bf16 on f32 A operand ----
// OUT_MODE: 0 = f32 linear [M][NOUT]; 2 = bf16 col-blocked [NOUT/32][M][32]
template<int K, int NOUT, int OUT_MODE>
__global__ void fcgemm_kernel(const float* __restrict__ Af,
                              const unsigned short* __restrict__ Bp,
                              const float* __restrict__ scale, const float* __restrict__ shift,
                              const float* __restrict__ bias, void* __restrict__ outp) {
  constexpr int NB = NOUT / 16;
  constexpr int KB = K / 32;
  int wave = (blockIdx.x * blockDim.x + threadIdx.x) >> 6;
  int lane = threadIdx.x & 63;
  int row0 = wave * 16;
  int arow = row0 + (lane & 15);
  int kgrp = lane >> 4;
  f32x4 acc[NB];
#pragma unroll
  for (int i = 0; i < NB; ++i) acc[i] = (f32x4){0.f, 0.f, 0.f, 0.f};
  const float* ap = Af + (long long)arow * K + kgrp * 8;
  const short8v* bp = (const short8v*)Bp;
#pragma unroll
  for (int kb = 0; kb < KB; ++kb) {
    int k0 = kb * 32;
    float4 v0 = *(const float4*)(ap + k0);
    float4 v1 = *(const float4*)(ap + k0 + 4);
    int kk = k0 + kgrp * 8;
    short8v a;
    a[0] = (short)f2bf(fmaxf(fmaf(v0.x, scale[kk + 0], shift[kk + 0]), 0.f));
    a[1] = (short)f2bf(fmaxf(fmaf(v0.y, scale[kk + 1], shift[kk + 1]), 0.f));
    a[2] = (short)f2bf(fmaxf(fmaf(v0.z, scale[kk + 2], shift[kk + 2]), 0.f));
    a[3] = (short)f2bf(fmaxf(fmaf(v0.w, scale[kk + 3], shift[kk + 3]), 0.f));
    a[4] = (short)f2bf(fmaxf(fmaf(v1.x, scale[kk + 4], shift[kk + 4]), 0.f));
    a[5] = (short)f2bf(fmaxf(fmaf(v1.y, scale[kk + 5], shift[kk + 5]), 0.f));
    a[6] = (short)f2bf(fmaxf(fmaf(v1.z, scale[kk + 6], shift[kk + 6]), 0.f));
    a[7] = (short)f2bf(fmaxf(fmaf(v1.w, scale[kk + 7], shift[kk + 7]), 0.f));
#pragma unroll
    for (int nb = 0; nb < NB; ++nb) {
      short8v b = bp[(kb * NB + nb) * 64 + lane];
      acc[nb] = __builtin_amdgcn_mfma_f32_16x16x32_bf16(a, b, acc[nb], 0, 0, 0);
    }
  }
  int r0 = (lane >> 4) * 4;
  int coll = lane & 15;
#pragma unroll
  for (int nb = 0; nb < NB; ++nb) {
    int col = nb * 16 + coll;
    float bv = bias[col];
#pragma unroll
    for (int r = 0; r < 4; ++r) {
      long long row = row0 + r0 + r;
      float v = acc[nb][r] + bv;
      if (OUT_MODE == 2)
        ((unsigned short*)outp)[((size_t)(col >> 5) * N_NODES + row) * 32 + (col & 31)] = f2bf(v);
      else ((float*)outp)[row * NOUT + col] = v;
    }
  }
}

template<int D>
__global__ void bn_finalize_kernel(const float* __restrict__ stats, const float* __restrict__ g,
                                   const float* __restrict__ be, float* scale, float* shift) {
  int f = threadIdx.x;
  if (f < D) {
    float mean = stats[f] * (1.0f / N_NODES);
    float var = stats[D + f] * (1.0f / N_NODES) - mean * mean;
    float rstd = rsqrtf(var + BN_EPS);
    float sc = g[f] * rstd;
    scale[f] = sc;
    shift[f] = be[f] - mean * sc;
  }
}

extern "C" void kernel_launch(void* const* d_in, const int* in_sizes, int n_in,
                              void* d_out, int out_size, void* d_ws, size_t ws_size,
                              hipStream_t stream) {
  const int N = N_NODES;
  const float* x = (const float*)d_in[0];
  const int* src[3] = {(const int*)d_in[1], (const int*)d_in[3], (const int*)d_in[5]};
  const int* dst[3] = {(const int*)d_in[2], (const int*)d_in[4], (const int*)d_in[6]};
  const int E[3] = {in_sizes[1], in_sizes[3], in_sizes[5]};
  const int E_tot = E[0] + E[1] + E[2];

  const float* w0[3] = {(const float*)d_in[7], (const float*)d_in[9], (const float*)d_in[11]};
  const float* b0[3] = {(const float*)d_in[8], (const float*)d_in[10], (const float*)d_in[12]};
  const float* bn0_g = (const float*)d_in[13];
  const float* bn0_b = (const float*)d_in[14];
  const float* fc0_w = (const float*)d_in[15];
  const float* fc0_b = (const float*)d_in[16];
  const float* w1[3] = {(const float*)d_in[17], (const float*)d_in[19], (const float*)d_in[21]};
  const float* b1[3] = {(const float*)d_in[18], (const float*)d_in[20], (const float*)d_in[22]};
  const float* bn1_g = (const float*)d_in[23];
  const float* bn1_b = (const float*)d_in[24];
  const float* fc1_w = (const float*)d_in[25];
  const float* fc1_b = (const float*)d_in[26];

  // ---- workspace layout ----
  char* p = (char*)d_ws;
  auto alloc = [&](size_t bytes) { char* r = p; p += (bytes + 255) & ~255ULL; return r; };
  int* cnt = (int*)alloc((size_t)6 * N * 4);                  // -> rs floats after rsqrt
  int* row_ptr = (int*)alloc((size_t)3 * (N + 1) * 4);
  int* bbase = (int*)alloc((size_t)3 * (NBKT + 1) * 4);
  unsigned short* es = (unsigned short*)alloc((size_t)E_tot * 2);
  unsigned short* wpk = (unsigned short*)alloc((size_t)(18432 + 36864 + 9216 + 16384) * 2);
  float* b0s = (float*)alloc(96 * 4);
  float* b1s = (float*)alloc(128 * 4);
  float* stats = (float*)alloc(256 * 4);
  float* scale = (float*)alloc(128 * 4);
  float* shift = (float*)alloc(128 * 4);
  unsigned short* aggC = (unsigned short*)alloc((size_t)N * 288 * 2);
  float* hsum = (float*)alloc((size_t)N * 128 * 4);            // also hosts tmp/Hist/xb early
  unsigned short* h1 = (unsigned short*)alloc((size_t)N * 96 * 2);  // col-blocked [3][N][32]

  unsigned short* B0p = wpk;                          // 192x96
  unsigned short* B1p = wpk + 18432;                  // 288x128
  unsigned short* fc0p = wpk + 18432 + 36864;         // 96x96
  unsigned short* fc1p = wpk + 18432 + 36864 + 9216;  // 128x128
  float* rs = (float*)cnt;

  // transient aliases inside hsum region (dead before gemm0 writes hsum)
  unsigned int* tmp = (unsigned int*)hsum;
  unsigned char* tmp8 = (unsigned char*)hsum;
  int* Hist = (int*)((char*)hsum + ((size_t)9 << 20));
  unsigned short* xb = (unsigned short*)hsum;         // col-blocked [2][N][32]

  const int B = 256;

  // ---- CSR build (dst sort) + cnt_in ----
  r1_hist_kernel<<<3 * NBL, 256, 0, stream>>>(dst[0], dst[1], dst[2], E[0], E[1], E[2], Hist);
  r2_scan_kernel<<<3, 256, 0, stream>>>(Hist, bbase, E[0], E[1], E[2]);
  r3_scatter_kernel<<<3 * NBL, 256, 0, stream>>>(dst[0], dst[1], dst[2], src[0], src[1], src[2],
                                                 E[0], E[1], E[2], Hist, tmp);
  r4_bucket_kernel<<<3 * NBKT, 256, 0, stream>>>(tmp, bbase, E[0], E[1], E[2], es, row_ptr, cnt);
  // ---- out-degree counts (src) ----
  r1_hist_kernel<<<3 * NBL, 256, 0, stream>>>(src[0], src[1], src[2], E[0], E[1], E[2], Hist);
  r2_scan_kernel<<<3, 256, 0, stream>>>(Hist, bbase, E[0], E[1], E[2]);
  r3b_scatter_kernel<<<3 * NBL, 256, 0, stream>>>(src[0], src[1], src[2], E[0], E[1], E[2],
                                                  Hist, tmp8);
  r4b_bucket_kernel<<<3 * NBKT, 256, 0, stream>>>(tmp8, bbase, E[0], E[1], E[2], cnt);
  rsqrt_inplace_kernel<<<cdiv(6 * N, B), B, 0, stream>>>(cnt, 6 * N);

  // ---- x -> bf16 col-blocked (in dead tmp region) ----
  f32_to_bf16_blk_kernel<<<cdiv((long long)N * 16, B), B, 0, stream>>>(x, xb);

  // ---- pack weights + bias sums ----
  for (int e = 0; e < 3; ++e) {
    pack_w_kernel<<<cdiv(64 * 96, B), B, 0, stream>>>(w0[e], B0p, 64, 96, e * 64, 6);
    pack_w_kernel<<<cdiv(96 * 128, B), B, 0, stream>>>(w1[e], B1p, 96, 128, e * 96, 8);
  }
  pack_w_kernel<<<cdiv(96 * 96, B), B, 0, stream>>>(fc0_w, fc0p, 96, 96, 0, 6);
  pack_w_kernel<<<cdiv(128 * 128, B), B, 0, stream>>>(fc1_w, fc1p, 128, 128, 0, 8);
  bias_sum_kernel<<<1, 96, 0, stream>>>(b0[0], b0[1], b0[2], b0s, 96);
  bias_sum_kernel<<<1, 128, 0, stream>>>(b1[0], b1[1], b1[2], b1s, 128);

  const int BPP = 3 * N / 4;  // 48000 blocks per slice phase

  // ---- layer 0: col-blocked gather (2 slices) -> aggC [N][192]; GEMM+stats; FC fused BN ----
  hipMemsetAsync(stats, 0, 2 * 96 * 4, stream);
  gather_blk_kernel<2, 64, 192><<<2 * BPP, 256, 0, stream>>>(
      xb, row_ptr, es, rs, aggC, E[0], E[0] + E[1]);
  gemm_kernel<192, 96, 0, 1><<<N / 64, B, 0, stream>>>(aggC, B0p, b0s, hsum, stats);
  bn_finalize_kernel<96><<<1, 128, 0, stream>>>(stats, bn0_g, bn0_b, scale, shift);
  fcgemm_kernel<96, 96, 2><<<N / 64, B, 0, stream>>>(hsum, fc0p, scale, shift, fc0_b, h1);

  // ---- layer 1: col-blocked gather (3 slices) -> aggC [N][288]; GEMM+stats; FC fused BN ----
  hipMemsetAsync(stats, 0, 2 * 128 * 4, stream);
  gather_blk_kernel<3, 96, 288><<<3 * BPP, 256, 0, stream>>>(
      h1, row_ptr, es, rs, aggC, E[0], E[0] + E[1]);
  gemm_kernel<288, 128, 0, 1><<<N / 64, B, 0, stream>>>(aggC, B1p, b1s, hsum, stats);
  bn_finalize_kernel<128><<<1, 128, 0, stream>>>(stats, bn1_g, bn1_b, scale, shift);
  fcgemm_kernel<128, 128, 0><<<N / 64, B, 0, stream>>>(hsum, fc1p, scale, shift, fc1_b,
                                                       (float*)d_out);
}

// Round 8
// 471.396 us; speedup vs baseline: 1.5380x; 1.5380x over previous
//
#include <hip/hip_runtime.h>
#include <hip/hip_bf16.h>

#define N_NODES 64000
#define BN_EPS 1e-5f
#define NBL 512      // radix blocks per type
#define NBKT 250     // coarse buckets = N_NODES / 256

typedef __attribute__((ext_vector_type(8))) short short8v;   // 8 bf16 (4 VGPRs)
typedef __attribute__((ext_vector_type(4))) float f32x4;

static inline int cdiv(long long a, int b) { return (int)((a + b - 1) / b); }

__device__ inline float bf2f(unsigned short u) {
  union { unsigned int i; float f; } v; v.i = ((unsigned int)u) << 16; return v.f;
}
__device__ inline unsigned short f2bf(float f) {
  __hip_bfloat16 h = __float2bfloat16(f);
  return *reinterpret_cast<unsigned short*>(&h);
}

// ================= atomic-free CSR build (two-level radix) =================
__global__ void r1_hist_kernel(const int* __restrict__ k0, const int* __restrict__ k1,
                               const int* __restrict__ k2, int E0, int E1, int E2,
                               int* __restrict__ Hist) {
  int t = blockIdx.x / NBL, blk = blockIdx.x - t * NBL;
  const int* key = t == 0 ? k0 : (t == 1 ? k1 : k2);
  int E = t == 0 ? E0 : (t == 1 ? E1 : E2);
  __shared__ int h[256];
  h[threadIdx.x] = 0;
  __syncthreads();
  int ch = (E + NBL - 1) / NBL;
  int lo = blk * ch, hi = min(lo + ch, E);
  for (int i = lo + threadIdx.x; i < hi; i += 256) atomicAdd(&h[key[i] >> 8], 1);
  __syncthreads();
  Hist[(t * NBL + blk) * 256 + threadIdx.x] = h[threadIdx.x];
}

__global__ void r2_scan_kernel(int* __restrict__ Hist, int* __restrict__ bbase,
                               int E0, int E1, int E2) {
  int t = blockIdx.x;
  int bin = threadIdx.x;
  int* H = Hist + (size_t)t * NBL * 256;
  int total = 0;
  for (int blk = 0; blk < NBL; ++blk) total += H[blk * 256 + bin];
  __shared__ int s[256];
  s[bin] = total;
  __syncthreads();
  for (int o = 1; o < 256; o <<= 1) {
    int a = (bin >= o) ? s[bin - o] : 0;
    __syncthreads();
    s[bin] += a;
    __syncthreads();
  }
  int base = s[bin] - total;
  if (bin <= NBKT) bbase[t * (NBKT + 1) + bin] = base;
  int run = base;
  for (int blk = 0; blk < NBL; ++blk) {
    int v = H[blk * 256 + bin];
    H[blk * 256 + bin] = run;
    run += v;
  }
}

__global__ void r3_scatter_kernel(const int* __restrict__ d0, const int* __restrict__ d1,
                                  const int* __restrict__ d2, const int* __restrict__ s0,
                                  const int* __restrict__ s1, const int* __restrict__ s2,
                                  int E0, int E1, int E2, const int* __restrict__ Hist,
                                  unsigned int* __restrict__ tmp) {
  int t = blockIdx.x / NBL, blk = blockIdx.x - t * NBL;
  const int* dst = t == 0 ? d0 : (t == 1 ? d1 : d2);
  const int* src = t == 0 ? s0 : (t == 1 ? s1 : s2);
  int E = t == 0 ? E0 : (t == 1 ? E1 : E2);
  unsigned int* tp = tmp + (t == 0 ? 0 : (t == 1 ? E0 : E0 + E1));
  __shared__ int off[256];
  off[threadIdx.x] = Hist[(t * NBL + blk) * 256 + threadIdx.x];
  __syncthreads();
  int ch = (E + NBL - 1) / NBL;
  int lo = blk * ch, hi = min(lo + ch, E);
  for (int i = lo + threadIdx.x; i < hi; i += 256) {
    int d = dst[i];
    int p = atomicAdd(&off[d >> 8], 1);
    tp[p] = ((unsigned)(d & 255) << 16) | (unsigned)src[i];
  }
}

// R4: per-bucket fine counting sort -> packed es (bf16(rs_out[src])<<16 | src),
//     row_ptr, cnt_in
__global__ void r4_bucket_kernel(const unsigned int* __restrict__ tmp,
                                 const int* __restrict__ bbase, int E0, int E1, int E2,
                                 const float* __restrict__ rs_out_base,
                                 unsigned int* __restrict__ es, int* __restrict__ row_ptr,
                                 int* __restrict__ cnt_in) {
  int t = blockIdx.x / NBKT, b = blockIdx.x - t * NBKT;
  const int* bb = bbase + t * (NBKT + 1);
  int teo = (t == 0 ? 0 : (t == 1 ? E0 : E0 + E1));
  int E = t == 0 ? E0 : (t == 1 ? E1 : E2);
  const unsigned int* tp = tmp + teo;
  unsigned int* esp = es + teo;
  const float* ro = rs_out_base + t * N_NODES;
  int lo = bb[b], hi = bb[b + 1];
  __shared__ int c[256], s[256];
  c[threadIdx.x] = 0;
  __syncthreads();
  for (int i = lo + threadIdx.x; i < hi; i += 256) atomicAdd(&c[tp[i] >> 16], 1);
  __syncthreads();
  int v = c[threadIdx.x];
  s[threadIdx.x] = v;
  __syncthreads();
  for (int o = 1; o < 256; o <<= 1) {
    int a = (threadIdx.x >= o) ? s[threadIdx.x - o] : 0;
    __syncthreads();
    s[threadIdx.x] += a;
    __syncthreads();
  }
  int excl = s[threadIdx.x] - v;
  int node = b * 256 + threadIdx.x;
  cnt_in[t * N_NODES + node] = v;
  row_ptr[t * (N_NODES + 1) + node] = lo + excl;
  if (b == NBKT - 1 && threadIdx.x == 255) row_ptr[t * (N_NODES + 1) + N_NODES] = E;
  __syncthreads();
  s[threadIdx.x] = lo + excl;
  __syncthreads();
  for (int i = lo + threadIdx.x; i < hi; i += 256) {
    unsigned int w = tp[i];
    int p = atomicAdd(&s[w >> 16], 1);
    unsigned int sid = w & 0xFFFF;
    unsigned int rb = (unsigned int)f2bf(ro[sid]);
    esp[p] = (rb << 16) | sid;
  }
}

__global__ void r3b_scatter_kernel(const int* __restrict__ s0, const int* __restrict__ s1,
                                   const int* __restrict__ s2, int E0, int E1, int E2,
                                   const int* __restrict__ Hist, unsigned char* __restrict__ tmp8) {
  int t = blockIdx.x / NBL, blk = blockIdx.x - t * NBL;
  const int* src = t == 0 ? s0 : (t == 1 ? s1 : s2);
  int E = t == 0 ? E0 : (t == 1 ? E1 : E2);
  unsigned char* tp = tmp8 + (t == 0 ? 0 : (t == 1 ? E0 : E0 + E1));
  __shared__ int off[256];
  off[threadIdx.x] = Hist[(t * NBL + blk) * 256 + threadIdx.x];
  __syncthreads();
  int ch = (E + NBL - 1) / NBL;
  int lo = blk * ch, hi = min(lo + ch, E);
  for (int i = lo + threadIdx.x; i < hi; i += 256) {
    int sv = src[i];
    int p = atomicAdd(&off[sv >> 8], 1);
    tp[p] = (unsigned char)(sv & 255);
  }
}

__global__ void r4b_bucket_kernel(const unsigned char* __restrict__ tmp8,
                                  const int* __restrict__ bbase, int E0, int E1, int E2,
                                  int* __restrict__ cnt_out) {
  int t = blockIdx.x / NBKT, b = blockIdx.x - t * NBKT;
  const int* bb = bbase + t * (NBKT + 1);
  const unsigned char* tp = tmp8 + (t == 0 ? 0 : (t == 1 ? E0 : E0 + E1));
  int lo = bb[b], hi = bb[b + 1];
  __shared__ int c[256];
  c[threadIdx.x] = 0;
  __syncthreads();
  for (int i = lo + threadIdx.x; i < hi; i += 256) atomicAdd(&c[tp[i]], 1);
  __syncthreads();
  int node = b * 256 + threadIdx.x;
  cnt_out[t * N_NODES + node] = c[threadIdx.x];
}

__global__ void rsqrt_inplace_kernel(void* buf, int n) {
  int i = blockIdx.x * blockDim.x + threadIdx.x;
  if (i < n) {
    int c = ((const int*)buf)[i];
    ((float*)buf)[i] = rsqrtf(fmaxf((float)c, 1.0f));
  }
}

__global__ void f32_to_bf16_kernel(const float* __restrict__ in, unsigned short* __restrict__ out,
                                   int n4) {
  int i = blockIdx.x * blockDim.x + threadIdx.x;
  if (i < n4) {
    float4 v = ((const float4*)in)[i];
    ushort4 o;
    o.x = f2bf(v.x); o.y = f2bf(v.y); o.z = f2bf(v.z); o.w = f2bf(v.w);
    ((ushort4*)out)[i] = o;
  }
}

__global__ void pack_w_kernel(const float* __restrict__ W, unsigned short* __restrict__ Bp,
                              int Ksrc, int NOUT, int k_off, int NB) {
  int idx = blockIdx.x * blockDim.x + threadIdx.x;
  if (idx >= Ksrc * NOUT) return;
  int kl = idx / NOUT, n = idx - kl * NOUT;
  int k = k_off + kl;
  int kb = k >> 5, nb = n >> 4;
  int lane = (((k >> 3) & 3) << 4) | (n & 15);
  int e = k & 7;
  Bp[(((kb * NB) + nb) * 64 + lane) * 8 + e] = f2bf(W[idx]);
}

__global__ void bias_sum_kernel(const float* a, const float* b, const float* c,
                                float* o, int n) {
  int i = blockIdx.x * blockDim.x + threadIdx.x;
  if (i < n) o[i] = a[i] + b[i] + c[i];
}

// ---- merged pull aggregation over 3 types, packed es, 4-edge ILP ----
template<int D, int STR>
__global__ __launch_bounds__(256) void gather3_kernel(
    const unsigned short* __restrict__ hb, const int* __restrict__ row_ptr_base,
    const unsigned int* __restrict__ es_base, const float* __restrict__ rs_in_base,
    unsigned short* __restrict__ out, int E0, int E01) {
  int gwid = (blockIdx.x * blockDim.x + threadIdx.x) >> 6;
  int lane = threadIdx.x & 63;
  if (gwid >= 3 * N_NODES) return;
  int t = (gwid >= N_NODES) + (gwid >= 2 * N_NODES);
  int node = gwid - t * N_NODES;
  int eoff = t == 0 ? 0 : (t == 1 ? E0 : E01);
  const int* row_ptr = row_ptr_base + t * (N_NODES + 1);
  const unsigned int* es = es_base + eoff;
  const float* rs_in = rs_in_base + t * N_NODES;

  int lo = row_ptr[node], hi = row_ptr[node + 1];
  const bool two = (D > 64) && (lane < D - 64);
  float a0 = 0.f, a1 = 0.f, a2 = 0.f, a3 = 0.f;
  float b0 = 0.f, b1 = 0.f, b2 = 0.f, b3 = 0.f;
  int e = lo;
  for (; e + 3 < hi; e += 4) {
    unsigned int w0 = es[e], w1 = es[e + 1], w2 = es[e + 2], w3 = es[e + 3];
    int s0 = w0 & 0xFFFF, s1 = w1 & 0xFFFF, s2 = w2 & 0xFFFF, s3 = w3 & 0xFFFF;
    float r0 = bf2f(w0 >> 16), r1 = bf2f(w1 >> 16), r2 = bf2f(w2 >> 16), r3 = bf2f(w3 >> 16);
    a0 += r0 * bf2f(hb[s0 * D + lane]);
    a1 += r1 * bf2f(hb[s1 * D + lane]);
    a2 += r2 * bf2f(hb[s2 * D + lane]);
    a3 += r3 * bf2f(hb[s3 * D + lane]);
    if (two) {
      b0 += r0 * bf2f(hb[s0 * D + 64 + lane]);
      b1 += r1 * bf2f(hb[s1 * D + 64 + lane]);
      b2 += r2 * bf2f(hb[s2 * D + 64 + lane]);
      b3 += r3 * bf2f(hb[s3 * D + 64 + lane]);
    }
  }
  for (; e < hi; ++e) {
    unsigned int w = es[e];
    int s = w & 0xFFFF;
    float r = bf2f(w >> 16);
    a0 += r * bf2f(hb[s * D + lane]);
    if (two) b0 += r * bf2f(hb[s * D + 64 + lane]);
  }
  float acc0 = (a0 + a1) + (a2 + a3);
  float ri = rs_in[node];
  unsigned short v0 = f2bf(acc0 * ri);
  __builtin_nontemporal_store(v0, &out[(size_t)node * STR + t * D + lane]);
  if (two) {
    float acc1 = (b0 + b1) + (b2 + b3);
    unsigned short v1 = f2bf(acc1 * ri);
    __builtin_nontemporal_store(v1, &out[(size_t)node * STR + t * D + 64 + lane]);
  }
}

// ---- MFMA GEMM with optional fused column-stats (sum, sumsq) epilogue ----
template<int K, int NOUT, int OUT_BF16, int STATS>
__global__ void gemm_kernel(const unsigned short* __restrict__ A,
                            const unsigned short* __restrict__ Bp,
                            const float* __restrict__ bias, void* __restrict__ outp,
                            float* __restrict__ stats) {
  constexpr int NB = NOUT / 16;
  constexpr int KB = K / 32;
  __shared__ float ls[STATS ? NOUT : 1], lq[STATS ? NOUT : 1];
  if (STATS) {
    for (int i = threadIdx.x; i < NOUT; i += blockDim.x) { ls[i] = 0.f; lq[i] = 0.f; }
    __syncthreads();
  }
  int wave = (blockIdx.x * blockDim.x + threadIdx.x) >> 6;
  int lane = threadIdx.x & 63;
  int row0 = wave * 16;
  int arow = row0 + (lane & 15);
  int kgrp = lane >> 4;
  f32x4 acc[NB];
#pragma unroll
  for (int i = 0; i < NB; ++i) acc[i] = (f32x4){0.f, 0.f, 0.f, 0.f};
  const short8v* ap = (const short8v*)(A + (long long)arow * K + kgrp * 8);
  const short8v* bp = (const short8v*)Bp;
#pragma unroll
  for (int kb = 0; kb < KB; ++kb) {
    short8v a = ap[kb * 4];
#pragma unroll
    for (int nb = 0; nb < NB; ++nb) {
      short8v b = bp[(kb * NB + nb) * 64 + lane];
      acc[nb] = __builtin_amdgcn_mfma_f32_16x16x32_bf16(a, b, acc[nb], 0, 0, 0);
    }
  }
  int r0 = (lane >> 4) * 4;
  int coll = lane & 15;
#pragma unroll
  for (int nb = 0; nb < NB; ++nb) {
    int col = nb * 16 + coll;
    float bv = bias[col];
    float s = 0.f, q = 0.f;
#pragma unroll
    for (int r = 0; r < 4; ++r) {
      long long row = row0 + r0 + r;
      float v = acc[nb][r] + bv;
      if (OUT_BF16) ((unsigned short*)outp)[row * NOUT + col] = f2bf(v);
      else ((float*)outp)[row * NOUT + col] = v;
      if (STATS) { s += v; q += v * v; }
    }
    if (STATS) {
      s += __shfl_xor(s, 16); q += __shfl_xor(q, 16);
      s += __shfl_xor(s, 32); q += __shfl_xor(q, 32);
      if (kgrp == 0) { atomicAdd(&ls[col], s); atomicAdd(&lq[col], q); }
    }
  }
  if (STATS) {
    __syncthreads();
    if (threadIdx.x < NOUT) {
      atomicAdd(&stats[threadIdx.x], ls[threadIdx.x]);
      atomicAdd(&stats[NOUT + threadIdx.x], lq[threadIdx.x]);
    }
  }
}

// ---- FC GEMM with fused BN->ReLU->bf16 on the f32 A operand ----
template<int K, int NOUT, int OUT_BF16>
__global__ void fcgemm_kernel(const float* __restrict__ Af,
                              const unsigned short* __restrict__ Bp,
                              const float* __restrict__ scale, const float* __restrict__ shift,
                              const float* __restrict__ bias, void* __restrict__ outp) {
  constexpr int NB = NOUT / 16;
  constexpr int KB = K / 32;
  int wave = (blockIdx.x * blockDim.x + threadIdx.x) >> 6;
  int lane = threadIdx.x & 63;
  int row0 = wave * 16;
  int arow = row0 + (lane & 15);
  int kgrp = lane >> 4;
  f32x4 acc[NB];
#pragma unroll
  for (int i = 0; i < NB; ++i) acc[i] = (f32x4){0.f, 0.f, 0.f, 0.f};
  const float* ap = Af + (long long)arow * K + kgrp * 8;
  const short8v* bp = (const short8v*)Bp;
#pragma unroll
  for (int kb = 0; kb < KB; ++kb) {
    int k0 = kb * 32;
    float4 v0 = *(const float4*)(ap + k0);
    float4 v1 = *(const float4*)(ap + k0 + 4);
    int kk = k0 + kgrp * 8;
    short8v a;
    a[0] = (short)f2bf(fmaxf(fmaf(v0.x, scale[kk + 0], shift[kk + 0]), 0.f));
    a[1] = (short)f2bf(fmaxf(fmaf(v0.y, scale[kk + 1], shift[kk + 1]), 0.f));
    a[2] = (short)f2bf(fmaxf(fmaf(v0.z, scale[kk + 2], shift[kk + 2]), 0.f));
    a[3] = (short)f2bf(fmaxf(fmaf(v0.w, scale[kk + 3], shift[kk + 3]), 0.f));
    a[4] = (short)f2bf(fmaxf(fmaf(v1.x, scale[kk + 4], shift[kk + 4]), 0.f));
    a[5] = (short)f2bf(fmaxf(fmaf(v1.y, scale[kk + 5], shift[kk + 5]), 0.f));
    a[6] = (short)f2bf(fmaxf(fmaf(v1.z, scale[kk + 6], shift[kk + 6]), 0.f));
    a[7] = (short)f2bf(fmaxf(fmaf(v1.w, scale[kk + 7], shift[kk + 7]), 0.f));
#pragma unroll
    for (int nb = 0; nb < NB; ++nb) {
      short8v b = bp[(kb * NB + nb) * 64 + lane];
      acc[nb] = __builtin_amdgcn_mfma_f32_16x16x32_bf16(a, b, acc[nb], 0, 0, 0);
    }
  }
  int r0 = (lane >> 4) * 4;
  int coll = lane & 15;
#pragma unroll
  for (int nb = 0; nb < NB; ++nb) {
    int col = nb * 16 + coll;
    float bv = bias[col];
#pragma unroll
    for (int r = 0; r < 4; ++r) {
      long long row = row0 + r0 + r;
      float v = acc[nb][r] + bv;
      if (OUT_BF16) ((unsigned short*)outp)[row * NOUT + col] = f2bf(v);
      else ((float*)outp)[row * NOUT + col] = v;
    }
  }
}

template<int D>
__global__ void bn_finalize_kernel(const float* __restrict__ stats, const float* __restrict__ g,
                                   const float* __restrict__ be, float* scale, float* shift) {
  int f = threadIdx.x;
  if (f < D) {
    float mean = stats[f] * (1.0f / N_NODES);
    float var = stats[D + f] * (1.0f / N_NODES) - mean * mean;
    float rstd = rsqrtf(var + BN_EPS);
    float sc = g[f] * rstd;
    scale[f] = sc;
    shift[f] = be[f] - mean * sc;
  }
}

extern "C" void kernel_launch(void* const* d_in, const int* in_sizes, int n_in,
                              void* d_out, int out_size, void* d_ws, size_t ws_size,
                              hipStream_t stream) {
  const int N = N_NODES;
  const float* x = (const float*)d_in[0];
  const int* src[3] = {(const int*)d_in[1], (const int*)d_in[3], (const int*)d_in[5]};
  const int* dst[3] = {(const int*)d_in[2], (const int*)d_in[4], (const int*)d_in[6]};
  const int E[3] = {in_sizes[1], in_sizes[3], in_sizes[5]};
  const int E_tot = E[0] + E[1] + E[2];

  const float* w0[3] = {(const float*)d_in[7], (const float*)d_in[9], (const float*)d_in[11]};
  const float* b0[3] = {(const float*)d_in[8], (const float*)d_in[10], (const float*)d_in[12]};
  const float* bn0_g = (const float*)d_in[13];
  const float* bn0_b = (const float*)d_in[14];
  const float* fc0_w = (const float*)d_in[15];
  const float* fc0_b = (const float*)d_in[16];
  const float* w1[3] = {(const float*)d_in[17], (const float*)d_in[19], (const float*)d_in[21]};
  const float* b1[3] = {(const float*)d_in[18], (const float*)d_in[20], (const float*)d_in[22]};
  const float* bn1_g = (const float*)d_in[23];
  const float* bn1_b = (const float*)d_in[24];
  const float* fc1_w = (const float*)d_in[25];
  const float* fc1_b = (const float*)d_in[26];

  // ---- workspace layout (~92.6 MB, within proven 93.2) ----
  char* p = (char*)d_ws;
  auto alloc = [&](size_t bytes) { char* r = p; p += (bytes + 255) & ~255ULL; return r; };
  int* cnt_out = (int*)alloc((size_t)3 * N * 4);   // -> rs_out floats
  int* cnt_in = (int*)alloc((size_t)3 * N * 4);    // -> rs_in floats
  int* row_ptr = (int*)alloc((size_t)3 * (N + 1) * 4);
  int* bbase = (int*)alloc((size_t)3 * (NBKT + 1) * 4);
  unsigned int* es = (unsigned int*)alloc((size_t)E_tot * 4);
  unsigned short* wpk = (unsigned short*)alloc((size_t)(18432 + 36864 + 9216 + 16384) * 2);
  float* b0s = (float*)alloc(96 * 4);
  float* b1s = (float*)alloc(128 * 4);
  float* stats = (float*)alloc(256 * 4);
  float* scale = (float*)alloc(128 * 4);
  float* shift = (float*)alloc(128 * 4);
  unsigned short* aggC = (unsigned short*)alloc((size_t)N * 288 * 2);
  float* hsum = (float*)alloc((size_t)N * 128 * 4);            // hosts tmp/Hist/xb early
  unsigned short* h1 = (unsigned short*)alloc((size_t)N * 96 * 2);

  unsigned short* B0p = wpk;                          // 192x96
  unsigned short* B1p = wpk + 18432;                  // 288x128
  unsigned short* fc0p = wpk + 18432 + 36864;         // 96x96
  unsigned short* fc1p = wpk + 18432 + 36864 + 9216;  // 128x128
  float* rs_out = (float*)cnt_out;
  float* rs_in = (float*)cnt_in;

  // transient aliases inside hsum region (dead before gemm0 writes hsum)
  unsigned int* tmp = (unsigned int*)hsum;                     // E_tot*4 = 8.19MB
  unsigned char* tmp8 = (unsigned char*)hsum;                  // E_tot
  int* Hist = (int*)((char*)hsum + ((size_t)9 << 20));         // 1.57MB @ 9MB
  unsigned short* xb = (unsigned short*)hsum;                  // 8.19MB (after tmp dead)

  const int B = 256;

  // ---- src-side sort first: out-degree counts -> rs_out ----
  r1_hist_kernel<<<3 * NBL, 256, 0, stream>>>(src[0], src[1], src[2], E[0], E[1], E[2], Hist);
  r2_scan_kernel<<<3, 256, 0, stream>>>(Hist, bbase, E[0], E[1], E[2]);
  r3b_scatter_kernel<<<3 * NBL, 256, 0, stream>>>(src[0], src[1], src[2], E[0], E[1], E[2],
                                                  Hist, tmp8);
  r4b_bucket_kernel<<<3 * NBKT, 256, 0, stream>>>(tmp8, bbase, E[0], E[1], E[2], cnt_out);
  rsqrt_inplace_kernel<<<cdiv(3 * N, B), B, 0, stream>>>(cnt_out, 3 * N);

  // ---- dst-side sort: packed es (rs_out folded in), row_ptr, cnt_in -> rs_in ----
  r1_hist_kernel<<<3 * NBL, 256, 0, stream>>>(dst[0], dst[1], dst[2], E[0], E[1], E[2], Hist);
  r2_scan_kernel<<<3, 256, 0, stream>>>(Hist, bbase, E[0], E[1], E[2]);
  r3_scatter_kernel<<<3 * NBL, 256, 0, stream>>>(dst[0], dst[1], dst[2], src[0], src[1], src[2],
                                                 E[0], E[1], E[2], Hist, tmp);
  r4_bucket_kernel<<<3 * NBKT, 256, 0, stream>>>(tmp, bbase, E[0], E[1], E[2], rs_out,
                                                 es, row_ptr, cnt_in);
  rsqrt_inplace_kernel<<<cdiv(3 * N, B), B, 0, stream>>>(cnt_in, 3 * N);

  // ---- x -> bf16 (in dead tmp region) ----
  f32_to_bf16_kernel<<<cdiv((long long)N * 16, B), B, 0, stream>>>(x, xb, N * 16);

  // ---- pack weights + bias sums ----
  for (int e = 0; e < 3; ++e) {
    pack_w_kernel<<<cdiv(64 * 96, B), B, 0, stream>>>(w0[e], B0p, 64, 96, e * 64, 6);
    pack_w_kernel<<<cdiv(96 * 128, B), B, 0, stream>>>(w1[e], B1p, 96, 128, e * 96, 8);
  }
  pack_w_kernel<<<cdiv(96 * 96, B), B, 0, stream>>>(fc0_w, fc0p, 96, 96, 0, 6);
  pack_w_kernel<<<cdiv(128 * 128, B), B, 0, stream>>>(fc1_w, fc1p, 128, 128, 0, 8);
  bias_sum_kernel<<<1, 96, 0, stream>>>(b0[0], b0[1], b0[2], b0s, 96);
  bias_sum_kernel<<<1, 128, 0, stream>>>(b1[0], b1[1], b1[2], b1s, 128);

  // ---- layer 0: merged gather (bf16 x, D=64) -> aggC [N][192]; GEMM+stats; FC fused BN ----
  hipMemsetAsync(stats, 0, 2 * 96 * 4, stream);
  gather3_kernel<64, 192><<<cdiv((long long)3 * N * 64, B), B, 0, stream>>>(
      xb, row_ptr, es, rs_in, aggC, E[0], E[0] + E[1]);
  gemm_kernel<192, 96, 0, 1><<<N / 64, B, 0, stream>>>(aggC, B0p, b0s, hsum, stats);
  bn_finalize_kernel<96><<<1, 128, 0, stream>>>(stats, bn0_g, bn0_b, scale, shift);
  fcgemm_kernel<96, 96, 1><<<N / 64, B, 0, stream>>>(hsum, fc0p, scale, shift, fc0_b, h1);

  // ---- layer 1: merged gather (bf16 h1, D=96) -> aggC [N][288]; GEMM+stats; FC fused BN ----
  hipMemsetAsync(stats, 0, 2 * 128 * 4, stream);
  gather3_kernel<96, 288><<<cdiv((long long)3 * N * 64, B), B, 0, stream>>>(
      h1, row_ptr, es, rs_in, aggC, E[0], E[0] + E[1]);
  gemm_kernel<288, 128, 0, 1><<<N / 64, B, 0, stream>>>(aggC, B1p, b1s, hsum, stats);
  bn_finalize_kernel<128><<<1, 128, 0, stream>>>(stats, bn1_g, bn1_b, scale, shift);
  fcgemm_kernel<128, 128, 0><<<N / 64, B, 0, stream>>>(hsum, fc1p, scale, shift, fc1_b,
                                                       (float*)d_out);
}

// Round 9
// 452.044 us; speedup vs baseline: 1.6038x; 1.0428x over previous
//
#include <hip/hip_runtime.h>
#include <hip/hip_bf16.h>

#define N_NODES 64000
#define BN_EPS 1e-5f
#define NBL 512      // radix blocks per type
#define NBKT 250     // coarse buckets = N_NODES / 256

typedef __attribute__((ext_vector_type(8))) short short8v;   // 8 bf16 (4 VGPRs)
typedef __attribute__((ext_vector_type(4))) float f32x4;

static inline int cdiv(long long a, int b) { return (int)((a + b - 1) / b); }

__device__ inline float bf2f(unsigned int u) {
  union { unsigned int i; float f; } v; v.i = u << 16; return v.f;
}
__device__ inline unsigned short f2bf(float f) {
  __hip_bfloat16 h = __float2bfloat16(f);
  return *reinterpret_cast<unsigned short*>(&h);
}

// ================= atomic-free CSR build (two-level radix) =================
__global__ void r1_hist_kernel(const int* __restrict__ k0, const int* __restrict__ k1,
                               const int* __restrict__ k2, int E0, int E1, int E2,
                               int* __restrict__ Hist) {
  int t = blockIdx.x / NBL, blk = blockIdx.x - t * NBL;
  const int* key = t == 0 ? k0 : (t == 1 ? k1 : k2);
  int E = t == 0 ? E0 : (t == 1 ? E1 : E2);
  __shared__ int h[256];
  h[threadIdx.x] = 0;
  __syncthreads();
  int ch = (E + NBL - 1) / NBL;
  int lo = blk * ch, hi = min(lo + ch, E);
  for (int i = lo + threadIdx.x; i < hi; i += 256) atomicAdd(&h[key[i] >> 8], 1);
  __syncthreads();
  Hist[(t * NBL + blk) * 256 + threadIdx.x] = h[threadIdx.x];
}

__global__ void r2_scan_kernel(int* __restrict__ Hist, int* __restrict__ bbase,
                               int E0, int E1, int E2) {
  int t = blockIdx.x;
  int bin = threadIdx.x;
  int* H = Hist + (size_t)t * NBL * 256;
  int total = 0;
  for (int blk = 0; blk < NBL; ++blk) total += H[blk * 256 + bin];
  __shared__ int s[256];
  s[bin] = total;
  __syncthreads();
  for (int o = 1; o < 256; o <<= 1) {
    int a = (bin >= o) ? s[bin - o] : 0;
    __syncthreads();
    s[bin] += a;
    __syncthreads();
  }
  int base = s[bin] - total;
  if (bin <= NBKT) bbase[t * (NBKT + 1) + bin] = base;
  int run = base;
  for (int blk = 0; blk < NBL; ++blk) {
    int v = H[blk * 256 + bin];
    H[blk * 256 + bin] = run;
    run += v;
  }
}

__global__ void r3_scatter_kernel(const int* __restrict__ d0, const int* __restrict__ d1,
                                  const int* __restrict__ d2, const int* __restrict__ s0,
                                  const int* __restrict__ s1, const int* __restrict__ s2,
                                  int E0, int E1, int E2, const int* __restrict__ Hist,
                                  unsigned int* __restrict__ tmp) {
  int t = blockIdx.x / NBL, blk = blockIdx.x - t * NBL;
  const int* dst = t == 0 ? d0 : (t == 1 ? d1 : d2);
  const int* src = t == 0 ? s0 : (t == 1 ? s1 : s2);
  int E = t == 0 ? E0 : (t == 1 ? E1 : E2);
  unsigned int* tp = tmp + (t == 0 ? 0 : (t == 1 ? E0 : E0 + E1));
  __shared__ int off[256];
  off[threadIdx.x] = Hist[(t * NBL + blk) * 256 + threadIdx.x];
  __syncthreads();
  int ch = (E + NBL - 1) / NBL;
  int lo = blk * ch, hi = min(lo + ch, E);
  for (int i = lo + threadIdx.x; i < hi; i += 256) {
    int d = dst[i];
    int p = atomicAdd(&off[d >> 8], 1);
    tp[p] = ((unsigned)(d & 255) << 16) | (unsigned)src[i];
  }
}

// R4: per-bucket fine counting sort -> packed es (bf16(rs_out[src])<<16 | src),
//     row_ptr, cnt_in
__global__ void r4_bucket_kernel(const unsigned int* __restrict__ tmp,
                                 const int* __restrict__ bbase, int E0, int E1, int E2,
                                 const float* __restrict__ rs_out_base,
                                 unsigned int* __restrict__ es, int* __restrict__ row_ptr,
                                 int* __restrict__ cnt_in) {
  int t = blockIdx.x / NBKT, b = blockIdx.x - t * NBKT;
  const int* bb = bbase + t * (NBKT + 1);
  int teo = (t == 0 ? 0 : (t == 1 ? E0 : E0 + E1));
  int E = t == 0 ? E0 : (t == 1 ? E1 : E2);
  const unsigned int* tp = tmp + teo;
  unsigned int* esp = es + teo;
  const float* ro = rs_out_base + t * N_NODES;
  int lo = bb[b], hi = bb[b + 1];
  __shared__ int c[256], s[256];
  c[threadIdx.x] = 0;
  __syncthreads();
  for (int i = lo + threadIdx.x; i < hi; i += 256) atomicAdd(&c[tp[i] >> 16], 1);
  __syncthreads();
  int v = c[threadIdx.x];
  s[threadIdx.x] = v;
  __syncthreads();
  for (int o = 1; o < 256; o <<= 1) {
    int a = (threadIdx.x >= o) ? s[threadIdx.x - o] : 0;
    __syncthreads();
    s[threadIdx.x] += a;
    __syncthreads();
  }
  int excl = s[threadIdx.x] - v;
  int node = b * 256 + threadIdx.x;
  cnt_in[t * N_NODES + node] = v;
  row_ptr[t * (N_NODES + 1) + node] = lo + excl;
  if (b == NBKT - 1 && threadIdx.x == 255) row_ptr[t * (N_NODES + 1) + N_NODES] = E;
  __syncthreads();
  s[threadIdx.x] = lo + excl;
  __syncthreads();
  for (int i = lo + threadIdx.x; i < hi; i += 256) {
    unsigned int w = tp[i];
    int p = atomicAdd(&s[w >> 16], 1);
    unsigned int sid = w & 0xFFFF;
    unsigned int rb = (unsigned int)f2bf(ro[sid]);
    esp[p] = (rb << 16) | sid;
  }
}

__global__ void r3b_scatter_kernel(const int* __restrict__ s0, const int* __restrict__ s1,
                                   const int* __restrict__ s2, int E0, int E1, int E2,
                                   const int* __restrict__ Hist, unsigned char* __restrict__ tmp8) {
  int t = blockIdx.x / NBL, blk = blockIdx.x - t * NBL;
  const int* src = t == 0 ? s0 : (t == 1 ? s1 : s2);
  int E = t == 0 ? E0 : (t == 1 ? E1 : E2);
  unsigned char* tp = tmp8 + (t == 0 ? 0 : (t == 1 ? E0 : E0 + E1));
  __shared__ int off[256];
  off[threadIdx.x] = Hist[(t * NBL + blk) * 256 + threadIdx.x];
  __syncthreads();
  int ch = (E + NBL - 1) / NBL;
  int lo = blk * ch, hi = min(lo + ch, E);
  for (int i = lo + threadIdx.x; i < hi; i += 256) {
    int sv = src[i];
    int p = atomicAdd(&off[sv >> 8], 1);
    tp[p] = (unsigned char)(sv & 255);
  }
}

__global__ void r4b_bucket_kernel(const unsigned char* __restrict__ tmp8,
                                  const int* __restrict__ bbase, int E0, int E1, int E2,
                                  int* __restrict__ cnt_out) {
  int t = blockIdx.x / NBKT, b = blockIdx.x - t * NBKT;
  const int* bb = bbase + t * (NBKT + 1);
  const unsigned char* tp = tmp8 + (t == 0 ? 0 : (t == 1 ? E0 : E0 + E1));
  int lo = bb[b], hi = bb[b + 1];
  __shared__ int c[256];
  c[threadIdx.x] = 0;
  __syncthreads();
  for (int i = lo + threadIdx.x; i < hi; i += 256) atomicAdd(&c[tp[i]], 1);
  __syncthreads();
  int node = b * 256 + threadIdx.x;
  cnt_out[t * N_NODES + node] = c[threadIdx.x];
}

__global__ void rsqrt_inplace_kernel(void* buf, int n) {
  int i = blockIdx.x * blockDim.x + threadIdx.x;
  if (i < n) {
    int c = ((const int*)buf)[i];
    ((float*)buf)[i] = rsqrtf(fmaxf((float)c, 1.0f));
  }
}

__global__ void f32_to_bf16_kernel(const float* __restrict__ in, unsigned short* __restrict__ out,
                                   int n4) {
  int i = blockIdx.x * blockDim.x + threadIdx.x;
  if (i < n4) {
    float4 v = ((const float4*)in)[i];
    ushort4 o;
    o.x = f2bf(v.x); o.y = f2bf(v.y); o.z = f2bf(v.z); o.w = f2bf(v.w);
    ((ushort4*)out)[i] = o;
  }
}

__global__ void pack_w_kernel(const float* __restrict__ W, unsigned short* __restrict__ Bp,
                              int Ksrc, int NOUT, int k_off, int NB) {
  int idx = blockIdx.x * blockDim.x + threadIdx.x;
  if (idx >= Ksrc * NOUT) return;
  int kl = idx / NOUT, n = idx - kl * NOUT;
  int k = k_off + kl;
  int kb = k >> 5, nb = n >> 4;
  int lane = (((k >> 3) & 3) << 4) | (n & 15);
  int e = k & 7;
  Bp[(((kb * NB) + nb) * 64 + lane) * 8 + e] = f2bf(W[idx]);
}

__global__ void bias_sum_kernel(const float* a, const float* b, const float* c,
                                float* o, int n) {
  int i = blockIdx.x * blockDim.x + threadIdx.x;
  if (i < n) o[i] = a[i] + b[i] + c[i];
}

// ---- merged pull aggregation: 2 half-wave slots x ILP4 = 8 edges in flight ----
// Features read as uint (2 bf16 cols per lane, 32 lanes = 64 cols).
// Slot s handles edges lo+s, lo+s+2, ...; combined via shfl_xor(32).
template<int D, int STR>
__global__ __launch_bounds__(256) void gather3_kernel(
    const unsigned int* __restrict__ hb32, const int* __restrict__ row_ptr_base,
    const unsigned int* __restrict__ es_base, const float* __restrict__ rs_in_base,
    unsigned int* __restrict__ out32, int E0, int E01) {
  constexpr int RW = D / 2;    // row width in uints (32 or 48)
  constexpr int SW = STR / 2;  // output row stride in uints
  int gwid = (blockIdx.x * blockDim.x + threadIdx.x) >> 6;
  int lane = threadIdx.x & 63;
  if (gwid >= 3 * N_NODES) return;
  int t = (gwid >= N_NODES) + (gwid >= 2 * N_NODES);
  int node = gwid - t * N_NODES;
  int eoff = t == 0 ? 0 : (t == 1 ? E0 : E01);
  const int* row_ptr = row_ptr_base + t * (N_NODES + 1);
  const unsigned int* es = es_base + eoff;
  const float* rs_in = rs_in_base + t * N_NODES;

  int slot = lane >> 5, c = lane & 31;
  const bool xtra = (D == 96) && (c < 16);
  int lo = row_ptr[node], hi = row_ptr[node + 1];

  float aL0 = 0.f, aL1 = 0.f, aL2 = 0.f, aL3 = 0.f;
  float aH0 = 0.f, aH1 = 0.f, aH2 = 0.f, aH3 = 0.f;
  float bL0 = 0.f, bL1 = 0.f, bL2 = 0.f, bL3 = 0.f;
  float bH0 = 0.f, bH1 = 0.f, bH2 = 0.f, bH3 = 0.f;

  int e = lo + slot;
  for (; e + 6 < hi; e += 8) {
    unsigned int w0 = es[e], w1 = es[e + 2], w2 = es[e + 4], w3 = es[e + 6];
    int s0 = w0 & 0xFFFF, s1 = w1 & 0xFFFF, s2 = w2 & 0xFFFF, s3 = w3 & 0xFFFF;
    float r0 = bf2f(w0 >> 16), r1 = bf2f(w1 >> 16), r2 = bf2f(w2 >> 16), r3 = bf2f(w3 >> 16);
    unsigned int u0 = hb32[s0 * RW + c], u1 = hb32[s1 * RW + c];
    unsigned int u2 = hb32[s2 * RW + c], u3 = hb32[s3 * RW + c];
    aL0 += r0 * bf2f(u0 & 0xFFFF); aH0 += r0 * bf2f(u0 >> 16);
    aL1 += r1 * bf2f(u1 & 0xFFFF); aH1 += r1 * bf2f(u1 >> 16);
    aL2 += r2 * bf2f(u2 & 0xFFFF); aH2 += r2 * bf2f(u2 >> 16);
    aL3 += r3 * bf2f(u3 & 0xFFFF); aH3 += r3 * bf2f(u3 >> 16);
    if (D == 96) {
      if (xtra) {
        unsigned int v0 = hb32[s0 * RW + 32 + c], v1 = hb32[s1 * RW + 32 + c];
        unsigned int v2 = hb32[s2 * RW + 32 + c], v3 = hb32[s3 * RW + 32 + c];
        bL0 += r0 * bf2f(v0 & 0xFFFF); bH0 += r0 * bf2f(v0 >> 16);
        bL1 += r1 * bf2f(v1 & 0xFFFF); bH1 += r1 * bf2f(v1 >> 16);
        bL2 += r2 * bf2f(v2 & 0xFFFF); bH2 += r2 * bf2f(v2 >> 16);
        bL3 += r3 * bf2f(v3 & 0xFFFF); bH3 += r3 * bf2f(v3 >> 16);
      }
    }
  }
  for (; e < hi; e += 2) {
    unsigned int w = es[e];
    int s = w & 0xFFFF;
    float r = bf2f(w >> 16);
    unsigned int u = hb32[s * RW + c];
    aL0 += r * bf2f(u & 0xFFFF); aH0 += r * bf2f(u >> 16);
    if (D == 96) {
      if (xtra) {
        unsigned int v = hb32[s * RW + 32 + c];
        bL0 += r * bf2f(v & 0xFFFF); bH0 += r * bf2f(v >> 16);
      }
    }
  }

  float aL = (aL0 + aL1) + (aL2 + aL3);
  float aH = (aH0 + aH1) + (aH2 + aH3);
  aL += __shfl_xor(aL, 32);
  aH += __shfl_xor(aH, 32);
  float bL = 0.f, bH = 0.f;
  if (D == 96) {
    bL = (bL0 + bL1) + (bL2 + bL3);
    bH = (bH0 + bH1) + (bH2 + bH3);
    bL += __shfl_xor(bL, 32);
    bH += __shfl_xor(bH, 32);
  }
  if (slot == 0) {
    float ri = rs_in[node];
    unsigned int o = ((unsigned int)f2bf(aH * ri) << 16) | (unsigned int)f2bf(aL * ri);
    __builtin_nontemporal_store(o, &out32[(size_t)node * SW + t * RW + c]);
    if (D == 96) {
      if (xtra) {
        unsigned int o2 = ((unsigned int)f2bf(bH * ri) << 16) | (unsigned int)f2bf(bL * ri);
        __builtin_nontemporal_store(o2, &out32[(size_t)node * SW + t * RW + 32 + c]);
      }
    }
  }
}

// ---- MFMA GEMM with optional fused column-stats (sum, sumsq) epilogue ----
template<int K, int NOUT, int OUT_BF16, int STATS>
__global__ void gemm_kernel(const unsigned short* __restrict__ A,
                            const unsigned short* __restrict__ Bp,
                            const float* __restrict__ bias, void* __restrict__ outp,
                            float* __restrict__ stats) {
  constexpr int NB = NOUT / 16;
  constexpr int KB = K / 32;
  __shared__ float ls[STATS ? NOUT : 1], lq[STATS ? NOUT : 1];
  if (STATS) {
    for (int i = threadIdx.x; i < NOUT; i += blockDim.x) { ls[i] = 0.f; lq[i] = 0.f; }
    __syncthreads();
  }
  int wave = (blockIdx.x * blockDim.x + threadIdx.x) >> 6;
  int lane = threadIdx.x & 63;
  int row0 = wave * 16;
  int arow = row0 + (lane & 15);
  int kgrp = lane >> 4;
  f32x4 acc[NB];
#pragma unroll
  for (int i = 0; i < NB; ++i) acc[i] = (f32x4){0.f, 0.f, 0.f, 0.f};
  const short8v* ap = (const short8v*)(A + (long long)arow * K + kgrp * 8);
  const short8v* bp = (const short8v*)Bp;
#pragma unroll
  for (int kb = 0; kb < KB; ++kb) {
    short8v a = ap[kb * 4];
#pragma unroll
    for (int nb = 0; nb < NB; ++nb) {
      short8v b = bp[(kb * NB + nb) * 64 + lane];
      acc[nb] = __builtin_amdgcn_mfma_f32_16x16x32_bf16(a, b, acc[nb], 0, 0, 0);
    }
  }
  int r0 = (lane >> 4) * 4;
  int coll = lane & 15;
#pragma unroll
  for (int nb = 0; nb < NB; ++nb) {
    int col = nb * 16 + coll;
    float bv = bias[col];
    float s = 0.f, q = 0.f;
#pragma unroll
    for (int r = 0; r < 4; ++r) {
      long long row = row0 + r0 + r;
      float v = acc[nb][r] + bv;
      if (OUT_BF16) ((unsigned short*)outp)[row * NOUT + col] = f2bf(v);
      else ((float*)outp)[row * NOUT + col] = v;
      if (STATS) { s += v; q += v * v; }
    }
    if (STATS) {
      s += __shfl_xor(s, 16); q += __shfl_xor(q, 16);
      s += __shfl_xor(s, 32); q += __shfl_xor(q, 32);
      if (kgrp == 0) { atomicAdd(&ls[col], s); atomicAdd(&lq[col], q); }
    }
  }
  if (STATS) {
    __syncthreads();
    if (threadIdx.x < NOUT) {
      atomicAdd(&stats[threadIdx.x], ls[threadIdx.x]);
      atomicAdd(&stats[NOUT + threadIdx.x], lq[threadIdx.x]);
    }
  }
}

// ---- FC GEMM with fused BN->ReLU->bf16 on the f32 A operand ----
template<int K, int NOUT, int OUT_BF16>
__global__ void fcgemm_kernel(const float* __restrict__ Af,
                              const unsigned short* __restrict__ Bp,
                              const float* __restrict__ scale, const float* __restrict__ shift,
                              const float* __restrict__ bias, void* __restrict__ outp) {
  constexpr int NB = NOUT / 16;
  constexpr int KB = K / 32;
  int wave = (blockIdx.x * blockDim.x + threadIdx.x) >> 6;
  int lane = threadIdx.x & 63;
  int row0 = wave * 16;
  int arow = row0 + (lane & 15);
  int kgrp = lane >> 4;
  f32x4 acc[NB];
#pragma unroll
  for (int i = 0; i < NB; ++i) acc[i] = (f32x4){0.f, 0.f, 0.f, 0.f};
  const float* ap = Af + (long long)arow * K + kgrp * 8;
  const short8v* bp = (const short8v*)Bp;
#pragma unroll
  for (int kb = 0; kb < KB; ++kb) {
    int k0 = kb * 32;
    float4 v0 = *(const float4*)(ap + k0);
    float4 v1 = *(const float4*)(ap + k0 + 4);
    int kk = k0 + kgrp * 8;
    short8v a;
    a[0] = (short)f2bf(fmaxf(fmaf(v0.x, scale[kk + 0], shift[kk + 0]), 0.f));
    a[1] = (short)f2bf(fmaxf(fmaf(v0.y, scale[kk + 1], shift[kk + 1]), 0.f));
    a[2] = (short)f2bf(fmaxf(fmaf(v0.z, scale[kk + 2], shift[kk + 2]), 0.f));
    a[3] = (short)f2bf(fmaxf(fmaf(v0.w, scale[kk + 3], shift[kk + 3]), 0.f));
    a[4] = (short)f2bf(fmaxf(fmaf(v1.x, scale[kk + 4], shift[kk + 4]), 0.f));
    a[5] = (short)f2bf(fmaxf(fmaf(v1.y, scale[kk + 5], shift[kk + 5]), 0.f));
    a[6] = (short)f2bf(fmaxf(fmaf(v1.z, scale[kk + 6], shift[kk + 6]), 0.f));
    a[7] = (short)f2bf(fmaxf(fmaf(v1.w, scale[kk + 7], shift[kk + 7]), 0.f));
#pragma unroll
    for (int nb = 0; nb < NB; ++nb) {
      short8v b = bp[(kb * NB + nb) * 64 + lane];
      acc[nb] = __builtin_amdgcn_mfma_f32_16x16x32_bf16(a, b, acc[nb], 0, 0, 0);
    }
  }
  int r0 = (lane >> 4) * 4;
  int coll = lane & 15;
#pragma unroll
  for (int nb = 0; nb < NB; ++nb) {
    int col = nb * 16 + coll;
    float bv = bias[col];
#pragma unroll
    for (int r = 0; r < 4; ++r) {
      long long row = row0 + r0 + r;
      float v = acc[nb][r] + bv;
      if (OUT_BF16) ((unsigned short*)outp)[row * NOUT + col] = f2bf(v);
      else ((float*)outp)[row * NOUT + col] = v;
    }
  }
}

template<int D>
__global__ void bn_finalize_kernel(const float* __restrict__ stats, const float* __restrict__ g,
                                   const float* __restrict__ be, float* scale, float* shift) {
  int f = threadIdx.x;
  if (f < D) {
    float mean = stats[f] * (1.0f / N_NODES);
    float var = stats[D + f] * (1.0f / N_NODES) - mean * mean;
    float rstd = rsqrtf(var + BN_EPS);
    float sc = g[f] * rstd;
    scale[f] = sc;
    shift[f] = be[f] - mean * sc;
  }
}

extern "C" void kernel_launch(void* const* d_in, const int* in_sizes, int n_in,
                              void* d_out, int out_size, void* d_ws, size_t ws_size,
                              hipStream_t stream) {
  const int N = N_NODES;
  const float* x = (const float*)d_in[0];
  const int* src[3] = {(const int*)d_in[1], (const int*)d_in[3], (const int*)d_in[5]};
  const int* dst[3] = {(const int*)d_in[2], (const int*)d_in[4], (const int*)d_in[6]};
  const int E[3] = {in_sizes[1], in_sizes[3], in_sizes[5]};
  const int E_tot = E[0] + E[1] + E[2];

  const float* w0[3] = {(const float*)d_in[7], (const float*)d_in[9], (const float*)d_in[11]};
  const float* b0[3] = {(const float*)d_in[8], (const float*)d_in[10], (const float*)d_in[12]};
  const float* bn0_g = (const float*)d_in[13];
  const float* bn0_b = (const float*)d_in[14];
  const float* fc0_w = (const float*)d_in[15];
  const float* fc0_b = (const float*)d_in[16];
  const float* w1[3] = {(const float*)d_in[17], (const float*)d_in[19], (const float*)d_in[21]};
  const float* b1[3] = {(const float*)d_in[18], (const float*)d_in[20], (const float*)d_in[22]};
  const float* bn1_g = (const float*)d_in[23];
  const float* bn1_b = (const float*)d_in[24];
  const float* fc1_w = (const float*)d_in[25];
  const float* fc1_b = (const float*)d_in[26];

  // ---- workspace layout (~92.6 MB, within proven 93.2) ----
  char* p = (char*)d_ws;
  auto alloc = [&](size_t bytes) { char* r = p; p += (bytes + 255) & ~255ULL; return r; };
  int* cnt_out = (int*)alloc((size_t)3 * N * 4);   // -> rs_out floats
  int* cnt_in = (int*)alloc((size_t)3 * N * 4);    // -> rs_in floats
  int* row_ptr = (int*)alloc((size_t)3 * (N + 1) * 4);
  int* bbase = (int*)alloc((size_t)3 * (NBKT + 1) * 4);
  unsigned int* es = (unsigned int*)alloc((size_t)E_tot * 4);
  unsigned short* wpk = (unsigned short*)alloc((size_t)(18432 + 36864 + 9216 + 16384) * 2);
  float* b0s = (float*)alloc(96 * 4);
  float* b1s = (float*)alloc(128 * 4);
  float* stats = (float*)alloc(256 * 4);
  float* scale = (float*)alloc(128 * 4);
  float* shift = (float*)alloc(128 * 4);
  unsigned short* aggC = (unsigned short*)alloc((size_t)N * 288 * 2);
  float* hsum = (float*)alloc((size_t)N * 128 * 4);            // hosts tmp/Hist/xb early
  unsigned short* h1 = (unsigned short*)alloc((size_t)N * 96 * 2);

  unsigned short* B0p = wpk;                          // 192x96
  unsigned short* B1p = wpk + 18432;                  // 288x128
  unsigned short* fc0p = wpk + 18432 + 36864;         // 96x96
  unsigned short* fc1p = wpk + 18432 + 36864 + 9216;  // 128x128
  float* rs_out = (float*)cnt_out;
  float* rs_in = (float*)cnt_in;

  // transient aliases inside hsum region (dead before gemm0 writes hsum)
  unsigned int* tmp = (unsigned int*)hsum;                     // E_tot*4 = 8.19MB
  unsigned char* tmp8 = (unsigned char*)hsum;                  // E_tot
  int* Hist = (int*)((char*)hsum + ((size_t)9 << 20));         // 1.57MB @ 9MB
  unsigned short* xb = (unsigned short*)hsum;                  // 8.19MB (after tmp dead)

  const int B = 256;

  // ---- src-side sort first: out-degree counts -> rs_out ----
  r1_hist_kernel<<<3 * NBL, 256, 0, stream>>>(src[0], src[1], src[2], E[0], E[1], E[2], Hist);
  r2_scan_kernel<<<3, 256, 0, stream>>>(Hist, bbase, E[0], E[1], E[2]);
  r3b_scatter_kernel<<<3 * NBL, 256, 0, stream>>>(src[0], src[1], src[2], E[0], E[1], E[2],
                                                  Hist, tmp8);
  r4b_bucket_kernel<<<3 * NBKT, 256, 0, stream>>>(tmp8, bbase, E[0], E[1], E[2], cnt_out);
  rsqrt_inplace_kernel<<<cdiv(3 * N, B), B, 0, stream>>>(cnt_out, 3 * N);

  // ---- dst-side sort: packed es (rs_out folded in), row_ptr, cnt_in -> rs_in ----
  r1_hist_kernel<<<3 * NBL, 256, 0, stream>>>(dst[0], dst[1], dst[2], E[0], E[1], E[2], Hist);
  r2_scan_kernel<<<3, 256, 0, stream>>>(Hist, bbase, E[0], E[1], E[2]);
  r3_scatter_kernel<<<3 * NBL, 256, 0, stream>>>(dst[0], dst[1], dst[2], src[0], src[1], src[2],
                                                 E[0], E[1], E[2], Hist, tmp);
  r4_bucket_kernel<<<3 * NBKT, 256, 0, stream>>>(tmp, bbase, E[0], E[1], E[2], rs_out,
                                                 es, row_ptr, cnt_in);
  rsqrt_inplace_kernel<<<cdiv(3 * N, B), B, 0, stream>>>(cnt_in, 3 * N);

  // ---- x -> bf16 (in dead tmp region) ----
  f32_to_bf16_kernel<<<cdiv((long long)N * 16, B), B, 0, stream>>>(x, xb, N * 16);

  // ---- pack weights + bias sums ----
  for (int e = 0; e < 3; ++e) {
    pack_w_kernel<<<cdiv(64 * 96, B), B, 0, stream>>>(w0[e], B0p, 64, 96, e * 64, 6);
    pack_w_kernel<<<cdiv(96 * 128, B), B, 0, stream>>>(w1[e], B1p, 96, 128, e * 96, 8);
  }
  pack_w_kernel<<<cdiv(96 * 96, B), B, 0, stream>>>(fc0_w, fc0p, 96, 96, 0, 6);
  pack_w_kernel<<<cdiv(128 * 128, B), B, 0, stream>>>(fc1_w, fc1p, 128, 128, 0, 8);
  bias_sum_kernel<<<1, 96, 0, stream>>>(b0[0], b0[1], b0[2], b0s, 96);
  bias_sum_kernel<<<1, 128, 0, stream>>>(b1[0], b1[1], b1[2], b1s, 128);

  // ---- layer 0: merged gather (bf16 x, D=64) -> aggC [N][192]; GEMM+stats; FC fused BN ----
  hipMemsetAsync(stats, 0, 2 * 96 * 4, stream);
  gather3_kernel<64, 192><<<cdiv((long long)3 * N * 64, B), B, 0, stream>>>(
      (const unsigned int*)xb, row_ptr, es, rs_in, (unsigned int*)aggC, E[0], E[0] + E[1]);
  gemm_kernel<192, 96, 0, 1><<<N / 64, B, 0, stream>>>(aggC, B0p, b0s, hsum, stats);
  bn_finalize_kernel<96><<<1, 128, 0, stream>>>(stats, bn0_g, bn0_b, scale, shift);
  fcgemm_kernel<96, 96, 1><<<N / 64, B, 0, stream>>>(hsum, fc0p, scale, shift, fc0_b, h1);

  // ---- layer 1: merged gather (bf16 h1, D=96) -> aggC [N][288]; GEMM+stats; FC fused BN ----
  hipMemsetAsync(stats, 0, 2 * 128 * 4, stream);
  gather3_kernel<96, 288><<<cdiv((long long)3 * N * 64, B), B, 0, stream>>>(
      (const unsigned int*)h1, row_ptr, es, rs_in, (unsigned int*)aggC, E[0], E[0] + E[1]);
  gemm_kernel<288, 128, 0, 1><<<N / 64, B, 0, stream>>>(aggC, B1p, b1s, hsum, stats);
  bn_finalize_kernel<128><<<1, 128, 0, stream>>>(stats, bn1_g, bn1_b, scale, shift);
  fcgemm_kernel<128, 128, 0><<<N / 64, B, 0, stream>>>(hsum, fc1p, scale, shift, fc1_b,
                                                       (float*)d_out);
}

// Round 10
// 437.384 us; speedup vs baseline: 1.6576x; 1.0335x over previous
//
#include <hip/hip_runtime.h>
#include <hip/hip_bf16.h>

#define N_NODES 64000
#define BN_EPS 1e-5f
#define NBL 512      // radix blocks per type
#define NBKT 250     // coarse buckets = N_NODES / 256

typedef __attribute__((ext_vector_type(8))) short short8v;   // 8 bf16 (4 VGPRs)
typedef __attribute__((ext_vector_type(4))) float f32x4;

static inline int cdiv(long long a, int b) { return (int)((a + b - 1) / b); }

__device__ inline float bf2f(unsigned int u) {
  union { unsigned int i; float f; } v; v.i = u << 16; return v.f;
}
__device__ inline unsigned short f2bf(float f) {
  __hip_bfloat16 h = __float2bfloat16(f);
  return *reinterpret_cast<unsigned short*>(&h);
}

// ================= atomic-free CSR build (two-level radix, merged) =================
// R1: per-(type,block) LDS histograms of src>>8 AND dst>>8 in one pass
__global__ void r1ab_kernel(const int* __restrict__ s0, const int* __restrict__ s1,
                            const int* __restrict__ s2, const int* __restrict__ d0,
                            const int* __restrict__ d1, const int* __restrict__ d2,
                            int E0, int E1, int E2,
                            int* __restrict__ HistS, int* __restrict__ HistD) {
  int t = blockIdx.x / NBL, blk = blockIdx.x - t * NBL;
  const int* src = t == 0 ? s0 : (t == 1 ? s1 : s2);
  const int* dst = t == 0 ? d0 : (t == 1 ? d1 : d2);
  int E = t == 0 ? E0 : (t == 1 ? E1 : E2);
  __shared__ int hs[256], hd[256];
  hs[threadIdx.x] = 0; hd[threadIdx.x] = 0;
  __syncthreads();
  int ch = (E + NBL - 1) / NBL;
  int lo = blk * ch, hi = min(lo + ch, E);
  for (int i = lo + threadIdx.x; i < hi; i += 256) {
    atomicAdd(&hs[src[i] >> 8], 1);
    atomicAdd(&hd[dst[i] >> 8], 1);
  }
  __syncthreads();
  HistS[(t * NBL + blk) * 256 + threadIdx.x] = hs[threadIdx.x];
  HistD[(t * NBL + blk) * 256 + threadIdx.x] = hd[threadIdx.x];
}

// R2: 6 blocks: 0-2 scan HistS -> bbaseS, 3-5 scan HistD -> bbaseD
__global__ void r2ab_kernel(int* __restrict__ HistS, int* __restrict__ HistD,
                            int* __restrict__ bbaseS, int* __restrict__ bbaseD) {
  int side = blockIdx.x / 3;   // 0 = src, 1 = dst
  int t = blockIdx.x - side * 3;
  int bin = threadIdx.x;
  int* H = (side ? HistD : HistS) + (size_t)t * NBL * 256;
  int* bb = (side ? bbaseD : bbaseS) + t * (NBKT + 1);
  int total = 0;
  for (int blk = 0; blk < NBL; ++blk) total += H[blk * 256 + bin];
  __shared__ int s[256];
  s[bin] = total;
  __syncthreads();
  for (int o = 1; o < 256; o <<= 1) {
    int a = (bin >= o) ? s[bin - o] : 0;
    __syncthreads();
    s[bin] += a;
    __syncthreads();
  }
  int base = s[bin] - total;
  if (bin <= NBKT) bb[bin] = base;
  int run = base;
  for (int blk = 0; blk < NBL; ++blk) {
    int v = H[blk * 256 + bin];
    H[blk * 256 + bin] = run;
    run += v;
  }
}

// R3: one pass scatters BOTH sides: tmp (dst-bucketed (dfine,src)) and tmp8 (src-bucketed sfine)
__global__ void r3ab_kernel(const int* __restrict__ s0, const int* __restrict__ s1,
                            const int* __restrict__ s2, const int* __restrict__ d0,
                            const int* __restrict__ d1, const int* __restrict__ d2,
                            int E0, int E1, int E2, const int* __restrict__ HistS,
                            const int* __restrict__ HistD, unsigned int* __restrict__ tmp,
                            unsigned char* __restrict__ tmp8) {
  int t = blockIdx.x / NBL, blk = blockIdx.x - t * NBL;
  const int* src = t == 0 ? s0 : (t == 1 ? s1 : s2);
  const int* dst = t == 0 ? d0 : (t == 1 ? d1 : d2);
  int E = t == 0 ? E0 : (t == 1 ? E1 : E2);
  int teo = (t == 0 ? 0 : (t == 1 ? E0 : E0 + E1));
  unsigned int* tp = tmp + teo;
  unsigned char* t8 = tmp8 + teo;
  __shared__ int offS[256], offD[256];
  offS[threadIdx.x] = HistS[(t * NBL + blk) * 256 + threadIdx.x];
  offD[threadIdx.x] = HistD[(t * NBL + blk) * 256 + threadIdx.x];
  __syncthreads();
  int ch = (E + NBL - 1) / NBL;
  int lo = blk * ch, hi = min(lo + ch, E);
  for (int i = lo + threadIdx.x; i < hi; i += 256) {
    int s = src[i], d = dst[i];
    int q = atomicAdd(&offS[s >> 8], 1);
    t8[q] = (unsigned char)(s & 255);
    int p = atomicAdd(&offD[d >> 8], 1);
    tp[p] = ((unsigned)(d & 255) << 16) | (unsigned)s;
  }
}

// R4b: per src-bucket fine counts -> rs_out (rsqrt folded in)
__global__ void r4b_kernel(const unsigned char* __restrict__ tmp8,
                           const int* __restrict__ bbaseS, int E0, int E1, int E2,
                           float* __restrict__ rs_out) {
  int t = blockIdx.x / NBKT, b = blockIdx.x - t * NBKT;
  const int* bb = bbaseS + t * (NBKT + 1);
  const unsigned char* tp = tmp8 + (t == 0 ? 0 : (t == 1 ? E0 : E0 + E1));
  int lo = bb[b], hi = bb[b + 1];
  __shared__ int c[256];
  c[threadIdx.x] = 0;
  __syncthreads();
  for (int i = lo + threadIdx.x; i < hi; i += 256) atomicAdd(&c[tp[i]], 1);
  __syncthreads();
  rs_out[t * N_NODES + b * 256 + threadIdx.x] = rsqrtf(fmaxf((float)c[threadIdx.x], 1.0f));
}

// R4: per dst-bucket fine counting sort -> packed es (bf16(rs_out[src])<<16|src),
//     row_ptr, rs_in (rsqrt folded in)
__global__ void r4_kernel(const unsigned int* __restrict__ tmp,
                          const int* __restrict__ bbaseD, int E0, int E1, int E2,
                          const float* __restrict__ rs_out_base,
                          unsigned int* __restrict__ es, int* __restrict__ row_ptr,
                          float* __restrict__ rs_in) {
  int t = blockIdx.x / NBKT, b = blockIdx.x - t * NBKT;
  const int* bb = bbaseD + t * (NBKT + 1);
  int teo = (t == 0 ? 0 : (t == 1 ? E0 : E0 + E1));
  int E = t == 0 ? E0 : (t == 1 ? E1 : E2);
  const unsigned int* tp = tmp + teo;
  unsigned int* esp = es + teo;
  const float* ro = rs_out_base + t * N_NODES;
  int lo = bb[b], hi = bb[b + 1];
  __shared__ int c[256], s[256];
  c[threadIdx.x] = 0;
  __syncthreads();
  for (int i = lo + threadIdx.x; i < hi; i += 256) atomicAdd(&c[tp[i] >> 16], 1);
  __syncthreads();
  int v = c[threadIdx.x];
  s[threadIdx.x] = v;
  __syncthreads();
  for (int o = 1; o < 256; o <<= 1) {
    int a = (threadIdx.x >= o) ? s[threadIdx.x - o] : 0;
    __syncthreads();
    s[threadIdx.x] += a;
    __syncthreads();
  }
  int excl = s[threadIdx.x] - v;
  int node = b * 256 + threadIdx.x;
  rs_in[t * N_NODES + node] = rsqrtf(fmaxf((float)v, 1.0f));
  row_ptr[t * (N_NODES + 1) + node] = lo + excl;
  if (b == NBKT - 1 && threadIdx.x == 255) row_ptr[t * (N_NODES + 1) + N_NODES] = E;
  __syncthreads();
  s[threadIdx.x] = lo + excl;
  __syncthreads();
  for (int i = lo + threadIdx.x; i < hi; i += 256) {
    unsigned int w = tp[i];
    int p = atomicAdd(&s[w >> 16], 1);
    unsigned int sid = w & 0xFFFF;
    unsigned int rb = (unsigned int)f2bf(ro[sid]);
    esp[p] = (rb << 16) | sid;
  }
}

// ================= one-shot prep: x->bf16, all weight packs, bias sums, stats zero ======
__device__ inline void pack_one(const float* __restrict__ W, unsigned short* __restrict__ Bp,
                                int idx, int NOUT, int k_off, int NB) {
  int kl = idx / NOUT, n = idx - kl * NOUT;
  int k = k_off + kl;
  int kb = k >> 5, nb = n >> 4;
  int lane = (((k >> 3) & 3) << 4) | (n & 15);
  int e = k & 7;
  Bp[(((kb * NB) + nb) * 64 + lane) * 8 + e] = f2bf(W[idx]);
}

#define XB_N (N_NODES * 16)

__global__ void prep_kernel(const float* __restrict__ x, unsigned short* __restrict__ xb,
                            const float* w00, const float* w01, const float* w02,
                            const float* w10, const float* w11, const float* w12,
                            const float* fc0w, const float* fc1w,
                            const float* b00, const float* b01, const float* b02,
                            const float* b10, const float* b11, const float* b12,
                            unsigned short* B0p, unsigned short* B1p,
                            unsigned short* fc0p, unsigned short* fc1p,
                            float* b0s, float* b1s, float* stats) {
  int idx = blockIdx.x * blockDim.x + threadIdx.x;
  if (idx < XB_N) {
    float4 v = ((const float4*)x)[idx];
    ushort4 o;
    o.x = f2bf(v.x); o.y = f2bf(v.y); o.z = f2bf(v.z); o.w = f2bf(v.w);
    ((ushort4*)xb)[idx] = o;
    return;
  }
  idx -= XB_N;
  if (idx < 3 * 6144) {
    int e = idx / 6144;
    pack_one(e == 0 ? w00 : (e == 1 ? w01 : w02), B0p, idx - e * 6144, 96, e * 64, 6);
    return;
  }
  idx -= 18432;
  if (idx < 3 * 12288) {
    int e = idx / 12288;
    pack_one(e == 0 ? w10 : (e == 1 ? w11 : w12), B1p, idx - e * 12288, 128, e * 96, 8);
    return;
  }
  idx -= 36864;
  if (idx < 9216) { pack_one(fc0w, fc0p, idx, 96, 0, 6); return; }
  idx -= 9216;
  if (idx < 16384) { pack_one(fc1w, fc1p, idx, 128, 0, 8); return; }
  idx -= 16384;
  if (idx < 96) { b0s[idx] = b00[idx] + b01[idx] + b02[idx]; return; }
  idx -= 96;
  if (idx < 128) { b1s[idx] = b10[idx] + b11[idx] + b12[idx]; return; }
  idx -= 128;
  if (idx < 256) { stats[idx] = 0.f; return; }
}

// ---- merged pull aggregation: 2 half-wave slots x ILP4 = 8 edges in flight ----
template<int D, int STR>
__global__ __launch_bounds__(256) void gather3_kernel(
    const unsigned int* __restrict__ hb32, const int* __restrict__ row_ptr_base,
    const unsigned int* __restrict__ es_base, const float* __restrict__ rs_in_base,
    unsigned int* __restrict__ out32, int E0, int E01) {
  constexpr int RW = D / 2;    // row width in uints (32 or 48)
  constexpr int SW = STR / 2;  // output row stride in uints
  int gwid = (blockIdx.x * blockDim.x + threadIdx.x) >> 6;
  int lane = threadIdx.x & 63;
  if (gwid >= 3 * N_NODES) return;
  int t = (gwid >= N_NODES) + (gwid >= 2 * N_NODES);
  int node = gwid - t * N_NODES;
  int eoff = t == 0 ? 0 : (t == 1 ? E0 : E01);
  const int* row_ptr = row_ptr_base + t * (N_NODES + 1);
  const unsigned int* es = es_base + eoff;
  const float* rs_in = rs_in_base + t * N_NODES;

  int slot = lane >> 5, c = lane & 31;
  const bool xtra = (D == 96) && (c < 16);
  int lo = row_ptr[node], hi = row_ptr[node + 1];

  float aL0 = 0.f, aL1 = 0.f, aL2 = 0.f, aL3 = 0.f;
  float aH0 = 0.f, aH1 = 0.f, aH2 = 0.f, aH3 = 0.f;
  float bL0 = 0.f, bL1 = 0.f, bL2 = 0.f, bL3 = 0.f;
  float bH0 = 0.f, bH1 = 0.f, bH2 = 0.f, bH3 = 0.f;

  int e = lo + slot;
  for (; e + 6 < hi; e += 8) {
    unsigned int w0 = __builtin_nontemporal_load(&es[e]);
    unsigned int w1 = __builtin_nontemporal_load(&es[e + 2]);
    unsigned int w2 = __builtin_nontemporal_load(&es[e + 4]);
    unsigned int w3 = __builtin_nontemporal_load(&es[e + 6]);
    int s0 = w0 & 0xFFFF, s1 = w1 & 0xFFFF, s2 = w2 & 0xFFFF, s3 = w3 & 0xFFFF;
    float r0 = bf2f(w0 >> 16), r1 = bf2f(w1 >> 16), r2 = bf2f(w2 >> 16), r3 = bf2f(w3 >> 16);
    unsigned int u0 = hb32[s0 * RW + c], u1 = hb32[s1 * RW + c];
    unsigned int u2 = hb32[s2 * RW + c], u3 = hb32[s3 * RW + c];
    aL0 += r0 * bf2f(u0 & 0xFFFF); aH0 += r0 * bf2f(u0 >> 16);
    aL1 += r1 * bf2f(u1 & 0xFFFF); aH1 += r1 * bf2f(u1 >> 16);
    aL2 += r2 * bf2f(u2 & 0xFFFF); aH2 += r2 * bf2f(u2 >> 16);
    aL3 += r3 * bf2f(u3 & 0xFFFF); aH3 += r3 * bf2f(u3 >> 16);
    if (D == 96) {
      if (xtra) {
        unsigned int v0 = hb32[s0 * RW + 32 + c], v1 = hb32[s1 * RW + 32 + c];
        unsigned int v2 = hb32[s2 * RW + 32 + c], v3 = hb32[s3 * RW + 32 + c];
        bL0 += r0 * bf2f(v0 & 0xFFFF); bH0 += r0 * bf2f(v0 >> 16);
        bL1 += r1 * bf2f(v1 & 0xFFFF); bH1 += r1 * bf2f(v1 >> 16);
        bL2 += r2 * bf2f(v2 & 0xFFFF); bH2 += r2 * bf2f(v2 >> 16);
        bL3 += r3 * bf2f(v3 & 0xFFFF); bH3 += r3 * bf2f(v3 >> 16);
      }
    }
  }
  for (; e < hi; e += 2) {
    unsigned int w = __builtin_nontemporal_load(&es[e]);
    int s = w & 0xFFFF;
    float r = bf2f(w >> 16);
    unsigned int u = hb32[s * RW + c];
    aL0 += r * bf2f(u & 0xFFFF); aH0 += r * bf2f(u >> 16);
    if (D == 96) {
      if (xtra) {
        unsigned int v = hb32[s * RW + 32 + c];
        bL0 += r * bf2f(v & 0xFFFF); bH0 += r * bf2f(v >> 16);
      }
    }
  }

  float aL = (aL0 + aL1) + (aL2 + aL3);
  float aH = (aH0 + aH1) + (aH2 + aH3);
  aL += __shfl_xor(aL, 32);
  aH += __shfl_xor(aH, 32);
  float bL = 0.f, bH = 0.f;
  if (D == 96) {
    bL = (bL0 + bL1) + (bL2 + bL3);
    bH = (bH0 + bH1) + (bH2 + bH3);
    bL += __shfl_xor(bL, 32);
    bH += __shfl_xor(bH, 32);
  }
  if (slot == 0) {
    float ri = rs_in[node];
    unsigned int o = ((unsigned int)f2bf(aH * ri) << 16) | (unsigned int)f2bf(aL * ri);
    __builtin_nontemporal_store(o, &out32[(size_t)node * SW + t * RW + c]);
    if (D == 96) {
      if (xtra) {
        unsigned int o2 = ((unsigned int)f2bf(bH * ri) << 16) | (unsigned int)f2bf(bL * ri);
        __builtin_nontemporal_store(o2, &out32[(size_t)node * SW + t * RW + 32 + c]);
      }
    }
  }
}

// ---- MFMA GEMM with optional fused column-stats (sum, sumsq) epilogue ----
template<int K, int NOUT, int OUT_BF16, int STATS>
__global__ void gemm_kernel(const unsigned short* __restrict__ A,
                            const unsigned short* __restrict__ Bp,
                            const float* __restrict__ bias, void* __restrict__ outp,
                            float* __restrict__ stats) {
  constexpr int NB = NOUT / 16;
  constexpr int KB = K / 32;
  __shared__ float ls[STATS ? NOUT : 1], lq[STATS ? NOUT : 1];
  if (STATS) {
    for (int i = threadIdx.x; i < NOUT; i += blockDim.x) { ls[i] = 0.f; lq[i] = 0.f; }
    __syncthreads();
  }
  int wave = (blockIdx.x * blockDim.x + threadIdx.x) >> 6;
  int lane = threadIdx.x & 63;
  int row0 = wave * 16;
  int arow = row0 + (lane & 15);
  int kgrp = lane >> 4;
  f32x4 acc[NB];
#pragma unroll
  for (int i = 0; i < NB; ++i) acc[i] = (f32x4){0.f, 0.f, 0.f, 0.f};
  const short8v* ap = (const short8v*)(A + (long long)arow * K + kgrp * 8);
  const short8v* bp = (const short8v*)Bp;
#pragma unroll
  for (int kb = 0; kb < KB; ++kb) {
    short8v a = ap[kb * 4];
#pragma unroll
    for (int nb = 0; nb < NB; ++nb) {
      short8v b = bp[(kb * NB + nb) * 64 + lane];
      acc[nb] = __builtin_amdgcn_mfma_f32_16x16x32_bf16(a, b, acc[nb], 0, 0, 0);
    }
  }
  int r0 = (lane >> 4) * 4;
  int coll = lane & 15;
#pragma unroll
  for (int nb = 0; nb < NB; ++nb) {
    int col = nb * 16 + coll;
    float bv = bias[col];
    float s = 0.f, q = 0.f;
#pragma unroll
    for (int r = 0; r < 4; ++r) {
      long long row = row0 + r0 + r;
      float v = acc[nb][r] + bv;
      if (OUT_BF16) ((unsigned short*)outp)[row * NOUT + col] = f2bf(v);
      else ((float*)outp)[row * NOUT + col] = v;
      if (STATS) { s += v; q += v * v; }
    }
    if (STATS) {
      s += __shfl_xor(s, 16); q += __shfl_xor(q, 16);
      s += __shfl_xor(s, 32); q += __shfl_xor(q, 32);
      if (kgrp == 0) { atomicAdd(&ls[col], s); atomicAdd(&lq[col], q); }
    }
  }
  if (STATS) {
    __syncthreads();
    if (threadIdx.x < NOUT) {
      atomicAdd(&stats[threadIdx.x], ls[threadIdx.x]);
      atomicAdd(&stats[NOUT + threadIdx.x], lq[threadIdx.x]);
    }
  }
}

// ---- FC GEMM with fused BN->ReLU->bf16 on the f32 A operand ----
template<int K, int NOUT, int OUT_BF16>
__global__ void fcgemm_kernel(const float* __restrict__ Af,
                              const unsigned short* __restrict__ Bp,
                              const float* __restrict__ scale, const float* __restrict__ shift,
                              const float* __restrict__ bias, void* __restrict__ outp) {
  constexpr int NB = NOUT / 16;
  constexpr int KB = K / 32;
  int wave = (blockIdx.x * blockDim.x + threadIdx.x) >> 6;
  int lane = threadIdx.x & 63;
  int row0 = wave * 16;
  int arow = row0 + (lane & 15);
  int kgrp = lane >> 4;
  f32x4 acc[NB];
#pragma unroll
  for (int i = 0; i < NB; ++i) acc[i] = (f32x4){0.f, 0.f, 0.f, 0.f};
  const float* ap = Af + (long long)arow * K + kgrp * 8;
  const short8v* bp = (const short8v*)Bp;
#pragma unroll
  for (int kb = 0; kb < KB; ++kb) {
    int k0 = kb * 32;
    float4 v0 = *(const float4*)(ap + k0);
    float4 v1 = *(const float4*)(ap + k0 + 4);
    int kk = k0 + kgrp * 8;
    short8v a;
    a[0] = (short)f2bf(fmaxf(fmaf(v0.x, scale[kk + 0], shift[kk + 0]), 0.f));
    a[1] = (short)f2bf(fmaxf(fmaf(v0.y, scale[kk + 1], shift[kk + 1]), 0.f));
    a[2] = (short)f2bf(fmaxf(fmaf(v0.z, scale[kk + 2], shift[kk + 2]), 0.f));
    a[3] = (short)f2bf(fmaxf(fmaf(v0.w, scale[kk + 3], shift[kk + 3]), 0.f));
    a[4] = (short)f2bf(fmaxf(fmaf(v1.x, scale[kk + 4], shift[kk + 4]), 0.f));
    a[5] = (short)f2bf(fmaxf(fmaf(v1.y, scale[kk + 5], shift[kk + 5]), 0.f));
    a[6] = (short)f2bf(fmaxf(fmaf(v1.z, scale[kk + 6], shift[kk + 6]), 0.f));
    a[7] = (short)f2bf(fmaxf(fmaf(v1.w, scale[kk + 7], shift[kk + 7]), 0.f));
#pragma unroll
    for (int nb = 0; nb < NB; ++nb) {
      short8v b = bp[(kb * NB + nb) * 64 + lane];
      acc[nb] = __builtin_amdgcn_mfma_f32_16x16x32_bf16(a, b, acc[nb], 0, 0, 0);
    }
  }
  int r0 = (lane >> 4) * 4;
  int coll = lane & 15;
#pragma unroll
  for (int nb = 0; nb < NB; ++nb) {
    int col = nb * 16 + coll;
    float bv = bias[col];
#pragma unroll
    for (int r = 0; r < 4; ++r) {
      long long row = row0 + r0 + r;
      float v = acc[nb][r] + bv;
      if (OUT_BF16) ((unsigned short*)outp)[row * NOUT + col] = f2bf(v);
      else ((float*)outp)[row * NOUT + col] = v;
    }
  }
}

// ---- BN finalize + clear stats for the next layer ----
template<int D>
__global__ void bn_finalize_kernel(float* __restrict__ stats, const float* __restrict__ g,
                                   const float* __restrict__ be, float* scale, float* shift) {
  int f = threadIdx.x;  // 128 threads
  float s0 = 0.f, s1 = 0.f;
  if (f < D) { s0 = stats[f]; s1 = stats[D + f]; }
  __syncthreads();
  stats[f] = 0.f;
  stats[128 + f] = 0.f;
  if (f < D) {
    float mean = s0 * (1.0f / N_NODES);
    float var = s1 * (1.0f / N_NODES) - mean * mean;
    float rstd = rsqrtf(var + BN_EPS);
    float sc = g[f] * rstd;
    scale[f] = sc;
    shift[f] = be[f] - mean * sc;
  }
}

extern "C" void kernel_launch(void* const* d_in, const int* in_sizes, int n_in,
                              void* d_out, int out_size, void* d_ws, size_t ws_size,
                              hipStream_t stream) {
  const int N = N_NODES;
  const float* x = (const float*)d_in[0];
  const int* src[3] = {(const int*)d_in[1], (const int*)d_in[3], (const int*)d_in[5]};
  const int* dst[3] = {(const int*)d_in[2], (const int*)d_in[4], (const int*)d_in[6]};
  const int E[3] = {in_sizes[1], in_sizes[3], in_sizes[5]};
  const int E_tot = E[0] + E[1] + E[2];

  const float* w0[3] = {(const float*)d_in[7], (const float*)d_in[9], (const float*)d_in[11]};
  const float* b0[3] = {(const float*)d_in[8], (const float*)d_in[10], (const float*)d_in[12]};
  const float* bn0_g = (const float*)d_in[13];
  const float* bn0_b = (const float*)d_in[14];
  const float* fc0_w = (const float*)d_in[15];
  const float* fc0_b = (const float*)d_in[16];
  const float* w1[3] = {(const float*)d_in[17], (const float*)d_in[19], (const float*)d_in[21]};
  const float* b1[3] = {(const float*)d_in[18], (const float*)d_in[20], (const float*)d_in[22]};
  const float* bn1_g = (const float*)d_in[23];
  const float* bn1_b = (const float*)d_in[24];
  const float* fc1_w = (const float*)d_in[25];
  const float* fc1_b = (const float*)d_in[26];

  // ---- workspace layout (~92 MB) ----
  char* p = (char*)d_ws;
  auto alloc = [&](size_t bytes) { char* r = p; p += (bytes + 255) & ~255ULL; return r; };
  float* rs_out = (float*)alloc((size_t)3 * N * 4);
  float* rs_in = (float*)alloc((size_t)3 * N * 4);
  int* row_ptr = (int*)alloc((size_t)3 * (N + 1) * 4);
  int* bbaseS = (int*)alloc((size_t)3 * (NBKT + 1) * 4);
  int* bbaseD = (int*)alloc((size_t)3 * (NBKT + 1) * 4);
  unsigned int* es = (unsigned int*)alloc((size_t)E_tot * 4);
  unsigned short* wpk = (unsigned short*)alloc((size_t)(18432 + 36864 + 9216 + 16384) * 2);
  float* b0s = (float*)alloc(96 * 4);
  float* b1s = (float*)alloc(128 * 4);
  float* stats = (float*)alloc(256 * 4);
  float* scale = (float*)alloc(128 * 4);
  float* shift = (float*)alloc(128 * 4);
  unsigned short* aggC = (unsigned short*)alloc((size_t)N * 288 * 2);
  float* hsum = (float*)alloc((size_t)N * 128 * 4);            // hosts tmp/tmp8/Hists/xb early
  unsigned short* h1 = (unsigned short*)alloc((size_t)N * 96 * 2);

  unsigned short* B0p = wpk;                          // 192x96
  unsigned short* B1p = wpk + 18432;                  // 288x128
  unsigned short* fc0p = wpk + 18432 + 36864;         // 96x96
  unsigned short* fc1p = wpk + 18432 + 36864 + 9216;  // 128x128

  // transient aliases inside hsum region (all dead before gemm0 writes hsum)
  unsigned int* tmp = (unsigned int*)hsum;                             // [0, 8.19MB)
  unsigned char* tmp8 = (unsigned char*)hsum + ((size_t)85 << 20 >> 3);// 8.5MB..10.6MB
  int* HistS = (int*)((char*)hsum + ((size_t)11 << 20));               // 1.57MB @ 11MB
  int* HistD = (int*)((char*)hsum + ((size_t)13 << 20));               // 1.57MB @ 13MB
  unsigned short* xb = (unsigned short*)hsum;                          // 8.19MB (after tmp dead)

  // ---- CSR build: merged histograms, merged scatters, rsqrt folded in ----
  r1ab_kernel<<<3 * NBL, 256, 0, stream>>>(src[0], src[1], src[2], dst[0], dst[1], dst[2],
                                           E[0], E[1], E[2], HistS, HistD);
  r2ab_kernel<<<6, 256, 0, stream>>>(HistS, HistD, bbaseS, bbaseD);
  r3ab_kernel<<<3 * NBL, 256, 0, stream>>>(src[0], src[1], src[2], dst[0], dst[1], dst[2],
                                           E[0], E[1], E[2], HistS, HistD, tmp, tmp8);
  r4b_kernel<<<3 * NBKT, 256, 0, stream>>>(tmp8, bbaseS, E[0], E[1], E[2], rs_out);
  r4_kernel<<<3 * NBKT, 256, 0, stream>>>(tmp, bbaseD, E[0], E[1], E[2], rs_out,
                                          es, row_ptr, rs_in);

  // ---- one-shot prep: x->bf16 (xb overlays dead tmp), weight packs, biases, stats=0 ----
  prep_kernel<<<cdiv(XB_N + 18432 + 36864 + 9216 + 16384 + 96 + 128 + 256, 256), 256, 0, stream>>>(
      x, xb, w0[0], w0[1], w0[2], w1[0], w1[1], w1[2], fc0_w, fc1_w,
      b0[0], b0[1], b0[2], b1[0], b1[1], b1[2], B0p, B1p, fc0p, fc1p, b0s, b1s, stats);

  const int B = 256;

  // ---- layer 0: merged gather (bf16 x, D=64) -> aggC [N][192]; GEMM+stats; FC fused BN ----
  gather3_kernel<64, 192><<<cdiv((long long)3 * N * 64, B), B, 0, stream>>>(
      (const unsigned int*)xb, row_ptr, es, rs_in, (unsigned int*)aggC, E[0], E[0] + E[1]);
  gemm_kernel<192, 96, 0, 1><<<N / 64, B, 0, stream>>>(aggC, B0p, b0s, hsum, stats);
  bn_finalize_kernel<96><<<1, 128, 0, stream>>>(stats, bn0_g, bn0_b, scale, shift);
  fcgemm_kernel<96, 96, 1><<<N / 64, B, 0, stream>>>(hsum, fc0p, scale, shift, fc0_b, h1);

  // ---- layer 1: merged gather (bf16 h1, D=96) -> aggC [N][288]; GEMM+stats; FC fused BN ----
  gather3_kernel<96, 288><<<cdiv((long long)3 * N * 64, B), B, 0, stream>>>(
      (const unsigned int*)h1, row_ptr, es, rs_in, (unsigned int*)aggC, E[0], E[0] + E[1]);
  gemm_kernel<288, 128, 0, 1><<<N / 64, B, 0, stream>>>(aggC, B1p, b1s, hsum, stats);
  bn_finalize_kernel<128><<<1, 128, 0, stream>>>(stats, bn1_g, bn1_b, scale, shift);
  fcgemm_kernel<128, 128, 0><<<N / 64, B, 0, stream>>>(hsum, fc1p, scale, shift, fc1_b,
                                                       (float*)d_out);
}

// Round 11
// 403.714 us; speedup vs baseline: 1.7958x; 1.0834x over previous
//
#include <hip/hip_runtime.h>
#include <hip/hip_bf16.h>

#define N_NODES 64000
#define BN_EPS 1e-5f
#define NBL 512      // radix blocks per type
#define NBKT 250     // coarse buckets = N_NODES / 256

typedef __attribute__((ext_vector_type(8))) short short8v;   // 8 bf16 (4 VGPRs)
typedef __attribute__((ext_vector_type(4))) float f32x4;

static inline int cdiv(long long a, int b) { return (int)((a + b - 1) / b); }

__device__ inline float bf2f(unsigned int u) {
  union { unsigned int i; float f; } v; v.i = u << 16; return v.f;
}
__device__ inline unsigned short f2bf(float f) {
  __hip_bfloat16 h = __float2bfloat16(f);
  return *reinterpret_cast<unsigned short*>(&h);
}

// ================= atomic-free CSR build (two-level radix, merged) =================
// R1: per-(type,block) LDS histograms of src>>8 AND dst>>8 in one pass
__global__ void r1ab_kernel(const int* __restrict__ s0, const int* __restrict__ s1,
                            const int* __restrict__ s2, const int* __restrict__ d0,
                            const int* __restrict__ d1, const int* __restrict__ d2,
                            int E0, int E1, int E2,
                            int* __restrict__ HistS, int* __restrict__ HistD) {
  int t = blockIdx.x / NBL, blk = blockIdx.x - t * NBL;
  const int* src = t == 0 ? s0 : (t == 1 ? s1 : s2);
  const int* dst = t == 0 ? d0 : (t == 1 ? d1 : d2);
  int E = t == 0 ? E0 : (t == 1 ? E1 : E2);
  __shared__ int hs[256], hd[256];
  hs[threadIdx.x] = 0; hd[threadIdx.x] = 0;
  __syncthreads();
  int ch = (E + NBL - 1) / NBL;
  int lo = blk * ch, hi = min(lo + ch, E);
  for (int i = lo + threadIdx.x; i < hi; i += 256) {
    atomicAdd(&hs[src[i] >> 8], 1);
    atomicAdd(&hd[dst[i] >> 8], 1);
  }
  __syncthreads();
  HistS[(t * NBL + blk) * 256 + threadIdx.x] = hs[threadIdx.x];
  HistD[(t * NBL + blk) * 256 + threadIdx.x] = hd[threadIdx.x];
}

// R2: 6 blocks: 0-2 scan HistS -> bbaseS, 3-5 scan HistD -> bbaseD
__global__ void r2ab_kernel(int* __restrict__ HistS, int* __restrict__ HistD,
                            int* __restrict__ bbaseS, int* __restrict__ bbaseD) {
  int side = blockIdx.x / 3;   // 0 = src, 1 = dst
  int t = blockIdx.x - side * 3;
  int bin = threadIdx.x;
  int* H = (side ? HistD : HistS) + (size_t)t * NBL * 256;
  int* bb = (side ? bbaseD : bbaseS) + t * (NBKT + 1);
  int total = 0;
  for (int blk = 0; blk < NBL; ++blk) total += H[blk * 256 + bin];
  __shared__ int s[256];
  s[bin] = total;
  __syncthreads();
  for (int o = 1; o < 256; o <<= 1) {
    int a = (bin >= o) ? s[bin - o] : 0;
    __syncthreads();
    s[bin] += a;
    __syncthreads();
  }
  int base = s[bin] - total;
  if (bin <= NBKT) bb[bin] = base;
  int run = base;
  for (int blk = 0; blk < NBL; ++blk) {
    int v = H[blk * 256 + bin];
    H[blk * 256 + bin] = run;
    run += v;
  }
}

// R3: one pass scatters BOTH sides: tmp (dst-bucketed (dfine,src)) and tmp8 (src-bucketed sfine)
__global__ void r3ab_kernel(const int* __restrict__ s0, const int* __restrict__ s1,
                            const int* __restrict__ s2, const int* __restrict__ d0,
                            const int* __restrict__ d1, const int* __restrict__ d2,
                            int E0, int E1, int E2, const int* __restrict__ HistS,
                            const int* __restrict__ HistD, unsigned int* __restrict__ tmp,
                            unsigned char* __restrict__ tmp8) {
  int t = blockIdx.x / NBL, blk = blockIdx.x - t * NBL;
  const int* src = t == 0 ? s0 : (t == 1 ? s1 : s2);
  const int* dst = t == 0 ? d0 : (t == 1 ? d1 : d2);
  int E = t == 0 ? E0 : (t == 1 ? E1 : E2);
  int teo = (t == 0 ? 0 : (t == 1 ? E0 : E0 + E1));
  unsigned int* tp = tmp + teo;
  unsigned char* t8 = tmp8 + teo;
  __shared__ int offS[256], offD[256];
  offS[threadIdx.x] = HistS[(t * NBL + blk) * 256 + threadIdx.x];
  offD[threadIdx.x] = HistD[(t * NBL + blk) * 256 + threadIdx.x];
  __syncthreads();
  int ch = (E + NBL - 1) / NBL;
  int lo = blk * ch, hi = min(lo + ch, E);
  for (int i = lo + threadIdx.x; i < hi; i += 256) {
    int s = src[i], d = dst[i];
    int q = atomicAdd(&offS[s >> 8], 1);
    t8[q] = (unsigned char)(s & 255);
    int p = atomicAdd(&offD[d >> 8], 1);
    tp[p] = ((unsigned)(d & 255) << 16) | (unsigned)s;
  }
}

// R4b: per src-bucket fine counts -> rs_out (rsqrt folded in)
__global__ void r4b_kernel(const unsigned char* __restrict__ tmp8,
                           const int* __restrict__ bbaseS, int E0, int E1, int E2,
                           float* __restrict__ rs_out) {
  int t = blockIdx.x / NBKT, b = blockIdx.x - t * NBKT;
  const int* bb = bbaseS + t * (NBKT + 1);
  const unsigned char* tp = tmp8 + (t == 0 ? 0 : (t == 1 ? E0 : E0 + E1));
  int lo = bb[b], hi = bb[b + 1];
  __shared__ int c[256];
  c[threadIdx.x] = 0;
  __syncthreads();
  for (int i = lo + threadIdx.x; i < hi; i += 256) atomicAdd(&c[tp[i]], 1);
  __syncthreads();
  rs_out[t * N_NODES + b * 256 + threadIdx.x] = rsqrtf(fmaxf((float)c[threadIdx.x], 1.0f));
}

// R4: per dst-bucket fine counting sort -> packed es (bf16(rs_out[src])<<16|src),
//     row_ptr, rs_in (rsqrt folded in)
__global__ void r4_kernel(const unsigned int* __restrict__ tmp,
                          const int* __restrict__ bbaseD, int E0, int E1, int E2,
                          const float* __restrict__ rs_out_base,
                          unsigned int* __restrict__ es, int* __restrict__ row_ptr,
                          float* __restrict__ rs_in) {
  int t = blockIdx.x / NBKT, b = blockIdx.x - t * NBKT;
  const int* bb = bbaseD + t * (NBKT + 1);
  int teo = (t == 0 ? 0 : (t == 1 ? E0 : E0 + E1));
  int E = t == 0 ? E0 : (t == 1 ? E1 : E2);
  const unsigned int* tp = tmp + teo;
  unsigned int* esp = es + teo;
  const float* ro = rs_out_base + t * N_NODES;
  int lo = bb[b], hi = bb[b + 1];
  __shared__ int c[256], s[256];
  c[threadIdx.x] = 0;
  __syncthreads();
  for (int i = lo + threadIdx.x; i < hi; i += 256) atomicAdd(&c[tp[i] >> 16], 1);
  __syncthreads();
  int v = c[threadIdx.x];
  s[threadIdx.x] = v;
  __syncthreads();
  for (int o = 1; o < 256; o <<= 1) {
    int a = (threadIdx.x >= o) ? s[threadIdx.x - o] : 0;
    __syncthreads();
    s[threadIdx.x] += a;
    __syncthreads();
  }
  int excl = s[threadIdx.x] - v;
  int node = b * 256 + threadIdx.x;
  rs_in[t * N_NODES + node] = rsqrtf(fmaxf((float)v, 1.0f));
  row_ptr[t * (N_NODES + 1) + node] = lo + excl;
  if (b == NBKT - 1 && threadIdx.x == 255) row_ptr[t * (N_NODES + 1) + N_NODES] = E;
  __syncthreads();
  s[threadIdx.x] = lo + excl;
  __syncthreads();
  for (int i = lo + threadIdx.x; i < hi; i += 256) {
    unsigned int w = tp[i];
    int p = atomicAdd(&s[w >> 16], 1);
    unsigned int sid = w & 0xFFFF;
    unsigned int rb = (unsigned int)f2bf(ro[sid]);
    esp[p] = (rb << 16) | sid;
  }
}

// ================= one-shot prep: x->bf16, all weight packs, bias sums, stats zero ======
__device__ inline void pack_one(const float* __restrict__ W, unsigned short* __restrict__ Bp,
                                int idx, int NOUT, int k_off, int NB) {
  int kl = idx / NOUT, n = idx - kl * NOUT;
  int k = k_off + kl;
  int kb = k >> 5, nb = n >> 4;
  int lane = (((k >> 3) & 3) << 4) | (n & 15);
  int e = k & 7;
  Bp[(((kb * NB) + nb) * 64 + lane) * 8 + e] = f2bf(W[idx]);
}

#define XB_N (N_NODES * 16)

__global__ void prep_kernel(const float* __restrict__ x, unsigned short* __restrict__ xb,
                            const float* w00, const float* w01, const float* w02,
                            const float* w10, const float* w11, const float* w12,
                            const float* fc0w, const float* fc1w,
                            const float* b00, const float* b01, const float* b02,
                            const float* b10, const float* b11, const float* b12,
                            unsigned short* B0p, unsigned short* B1p,
                            unsigned short* fc0p, unsigned short* fc1p,
                            float* b0s, float* b1s, float* stats) {
  int idx = blockIdx.x * blockDim.x + threadIdx.x;
  if (idx < XB_N) {
    float4 v = ((const float4*)x)[idx];
    ushort4 o;
    o.x = f2bf(v.x); o.y = f2bf(v.y); o.z = f2bf(v.z); o.w = f2bf(v.w);
    ((ushort4*)xb)[idx] = o;
    return;
  }
  idx -= XB_N;
  if (idx < 3 * 6144) {
    int e = idx / 6144;
    pack_one(e == 0 ? w00 : (e == 1 ? w01 : w02), B0p, idx - e * 6144, 96, e * 64, 6);
    return;
  }
  idx -= 18432;
  if (idx < 3 * 12288) {
    int e = idx / 12288;
    pack_one(e == 0 ? w10 : (e == 1 ? w11 : w12), B1p, idx - e * 12288, 128, e * 96, 8);
    return;
  }
  idx -= 36864;
  if (idx < 9216) { pack_one(fc0w, fc0p, idx, 96, 0, 6); return; }
  idx -= 9216;
  if (idx < 16384) { pack_one(fc1w, fc1p, idx, 128, 0, 8); return; }
  idx -= 16384;
  if (idx < 96) { b0s[idx] = b00[idx] + b01[idx] + b02[idx]; return; }
  idx -= 96;
  if (idx < 128) { b1s[idx] = b10[idx] + b11[idx] + b12[idx]; return; }
  idx -= 128;
  if (idx < 256) { stats[idx] = 0.f; return; }
}

// ---- merged pull aggregation: 2 half-wave slots x ILP4 = 8 edges in flight ----
template<int D, int STR>
__global__ __launch_bounds__(256) void gather3_kernel(
    const unsigned int* __restrict__ hb32, const int* __restrict__ row_ptr_base,
    const unsigned int* __restrict__ es_base, const float* __restrict__ rs_in_base,
    unsigned int* __restrict__ out32, int E0, int E01) {
  constexpr int RW = D / 2;    // row width in uints (32 or 48)
  constexpr int SW = STR / 2;  // output row stride in uints
  int gwid = (blockIdx.x * blockDim.x + threadIdx.x) >> 6;
  int lane = threadIdx.x & 63;
  if (gwid >= 3 * N_NODES) return;
  int t = (gwid >= N_NODES) + (gwid >= 2 * N_NODES);
  int node = gwid - t * N_NODES;
  int eoff = t == 0 ? 0 : (t == 1 ? E0 : E01);
  const int* row_ptr = row_ptr_base + t * (N_NODES + 1);
  const unsigned int* es = es_base + eoff;
  const float* rs_in = rs_in_base + t * N_NODES;

  int slot = lane >> 5, c = lane & 31;
  const bool xtra = (D == 96) && (c < 16);
  int lo = row_ptr[node], hi = row_ptr[node + 1];

  float aL0 = 0.f, aL1 = 0.f, aL2 = 0.f, aL3 = 0.f;
  float aH0 = 0.f, aH1 = 0.f, aH2 = 0.f, aH3 = 0.f;
  float bL0 = 0.f, bL1 = 0.f, bL2 = 0.f, bL3 = 0.f;
  float bH0 = 0.f, bH1 = 0.f, bH2 = 0.f, bH3 = 0.f;

  int e = lo + slot;
  for (; e + 6 < hi; e += 8) {
    unsigned int w0 = es[e], w1 = es[e + 2], w2 = es[e + 4], w3 = es[e + 6];
    int s0 = w0 & 0xFFFF, s1 = w1 & 0xFFFF, s2 = w2 & 0xFFFF, s3 = w3 & 0xFFFF;
    float r0 = bf2f(w0 >> 16), r1 = bf2f(w1 >> 16), r2 = bf2f(w2 >> 16), r3 = bf2f(w3 >> 16);
    unsigned int u0 = hb32[s0 * RW + c], u1 = hb32[s1 * RW + c];
    unsigned int u2 = hb32[s2 * RW + c], u3 = hb32[s3 * RW + c];
    aL0 += r0 * bf2f(u0 & 0xFFFF); aH0 += r0 * bf2f(u0 >> 16);
    aL1 += r1 * bf2f(u1 & 0xFFFF); aH1 += r1 * bf2f(u1 >> 16);
    aL2 += r2 * bf2f(u2 & 0xFFFF); aH2 += r2 * bf2f(u2 >> 16);
    aL3 += r3 * bf2f(u3 & 0xFFFF); aH3 += r3 * bf2f(u3 >> 16);
    if (D == 96) {
      if (xtra) {
        unsigned int v0 = hb32[s0 * RW + 32 + c], v1 = hb32[s1 * RW + 32 + c];
        unsigned int v2 = hb32[s2 * RW + 32 + c], v3 = hb32[s3 * RW + 32 + c];
        bL0 += r0 * bf2f(v0 & 0xFFFF); bH0 += r0 * bf2f(v0 >> 16);
        bL1 += r1 * bf2f(v1 & 0xFFFF); bH1 += r1 * bf2f(v1 >> 16);
        bL2 += r2 * bf2f(v2 & 0xFFFF); bH2 += r2 * bf2f(v2 >> 16);
        bL3 += r3 * bf2f(v3 & 0xFFFF); bH3 += r3 * bf2f(v3 >> 16);
      }
    }
  }
  for (; e < hi; e += 2) {
    unsigned int w = es[e];
    int s = w & 0xFFFF;
    float r = bf2f(w >> 16);
    unsigned int u = hb32[s * RW + c];
    aL0 += r * bf2f(u & 0xFFFF); aH0 += r * bf2f(u >> 16);
    if (D == 96) {
      if (xtra) {
        unsigned int v = hb32[s * RW + 32 + c];
        bL0 += r * bf2f(v & 0xFFFF); bH0 += r * bf2f(v >> 16);
      }
    }
  }

  float aL = (aL0 + aL1) + (aL2 + aL3);
  float aH = (aH0 + aH1) + (aH2 + aH3);
  aL += __shfl_xor(aL, 32);
  aH += __shfl_xor(aH, 32);
  float bL = 0.f, bH = 0.f;
  if (D == 96) {
    bL = (bL0 + bL1) + (bL2 + bL3);
    bH = (bH0 + bH1) + (bH2 + bH3);
    bL += __shfl_xor(bL, 32);
    bH += __shfl_xor(bH, 32);
  }
  if (slot == 0) {
    float ri = rs_in[node];
    unsigned int o = ((unsigned int)f2bf(aH * ri) << 16) | (unsigned int)f2bf(aL * ri);
    __builtin_nontemporal_store(o, &out32[(size_t)node * SW + t * RW + c]);
    if (D == 96) {
      if (xtra) {
        unsigned int o2 = ((unsigned int)f2bf(bH * ri) << 16) | (unsigned int)f2bf(bL * ri);
        __builtin_nontemporal_store(o2, &out32[(size_t)node * SW + t * RW + 32 + c]);
      }
    }
  }
}

// ---- MFMA GEMM with optional fused column-stats (sum, sumsq) epilogue ----
template<int K, int NOUT, int OUT_BF16, int STATS>
__global__ void gemm_kernel(const unsigned short* __restrict__ A,
                            const unsigned short* __restrict__ Bp,
                            const float* __restrict__ bias, void* __restrict__ outp,
                            float* __restrict__ stats) {
  constexpr int NB = NOUT / 16;
  constexpr int KB = K / 32;
  __shared__ float ls[STATS ? NOUT : 1], lq[STATS ? NOUT : 1];
  if (STATS) {
    for (int i = threadIdx.x; i < NOUT; i += blockDim.x) { ls[i] = 0.f; lq[i] = 0.f; }
    __syncthreads();
  }
  int wave = (blockIdx.x * blockDim.x + threadIdx.x) >> 6;
  int lane = threadIdx.x & 63;
  int row0 = wave * 16;
  int arow = row0 + (lane & 15);
  int kgrp = lane >> 4;
  f32x4 acc[NB];
#pragma unroll
  for (int i = 0; i < NB; ++i) acc[i] = (f32x4){0.f, 0.f, 0.f, 0.f};
  const short8v* ap = (const short8v*)(A + (long long)arow * K + kgrp * 8);
  const short8v* bp = (const short8v*)Bp;
#pragma unroll
  for (int kb = 0; kb < KB; ++kb) {
    short8v a = ap[kb * 4];
#pragma unroll
    for (int nb = 0; nb < NB; ++nb) {
      short8v b = bp[(kb * NB + nb) * 64 + lane];
      acc[nb] = __builtin_amdgcn_mfma_f32_16x16x32_bf16(a, b, acc[nb], 0, 0, 0);
    }
  }
  int r0 = (lane >> 4) * 4;
  int coll = lane & 15;
#pragma unroll
  for (int nb = 0; nb < NB; ++nb) {
    int col = nb * 16 + coll;
    float bv = bias[col];
    float s = 0.f, q = 0.f;
#pragma unroll
    for (int r = 0; r < 4; ++r) {
      long long row = row0 + r0 + r;
      float v = acc[nb][r] + bv;
      if (OUT_BF16) ((unsigned short*)outp)[row * NOUT + col] = f2bf(v);
      else ((float*)outp)[row * NOUT + col] = v;
      if (STATS) { s += v; q += v * v; }
    }
    if (STATS) {
      s += __shfl_xor(s, 16); q += __shfl_xor(q, 16);
      s += __shfl_xor(s, 32); q += __shfl_xor(q, 32);
      if (kgrp == 0) { atomicAdd(&ls[col], s); atomicAdd(&lq[col], q); }
    }
  }
  if (STATS) {
    __syncthreads();
    if (threadIdx.x < NOUT) {
      atomicAdd(&stats[threadIdx.x], ls[threadIdx.x]);
      atomicAdd(&stats[NOUT + threadIdx.x], lq[threadIdx.x]);
    }
  }
}

// ---- FC GEMM with fused BN->ReLU->bf16 on the f32 A operand ----
template<int K, int NOUT, int OUT_BF16>
__global__ void fcgemm_kernel(const float* __restrict__ Af,
                              const unsigned short* __restrict__ Bp,
                              const float* __restrict__ scale, const float* __restrict__ shift,
                              const float* __restrict__ bias, void* __restrict__ outp) {
  constexpr int NB = NOUT / 16;
  constexpr int KB = K / 32;
  int wave = (blockIdx.x * blockDim.x + threadIdx.x) >> 6;
  int lane = threadIdx.x & 63;
  int row0 = wave * 16;
  int arow = row0 + (lane & 15);
  int kgrp = lane >> 4;
  f32x4 acc[NB];
#pragma unroll
  for (int i = 0; i < NB; ++i) acc[i] = (f32x4){0.f, 0.f, 0.f, 0.f};
  const float* ap = Af + (long long)arow * K + kgrp * 8;
  const short8v* bp = (const short8v*)Bp;
#pragma unroll
  for (int kb = 0; kb < KB; ++kb) {
    int k0 = kb * 32;
    float4 v0 = *(const float4*)(ap + k0);
    float4 v1 = *(const float4*)(ap + k0 + 4);
    int kk = k0 + kgrp * 8;
    short8v a;
    a[0] = (short)f2bf(fmaxf(fmaf(v0.x, scale[kk + 0], shift[kk + 0]), 0.f));
    a[1] = (short)f2bf(fmaxf(fmaf(v0.y, scale[kk + 1], shift[kk + 1]), 0.f));
    a[2] = (short)f2bf(fmaxf(fmaf(v0.z, scale[kk + 2], shift[kk + 2]), 0.f));
    a[3] = (short)f2bf(fmaxf(fmaf(v0.w, scale[kk + 3], shift[kk + 3]), 0.f));
    a[4] = (short)f2bf(fmaxf(fmaf(v1.x, scale[kk + 4], shift[kk + 4]), 0.f));
    a[5] = (short)f2bf(fmaxf(fmaf(v1.y, scale[kk + 5], shift[kk + 5]), 0.f));
    a[6] = (short)f2bf(fmaxf(fmaf(v1.z, scale[kk + 6], shift[kk + 6]), 0.f));
    a[7] = (short)f2bf(fmaxf(fmaf(v1.w, scale[kk + 7], shift[kk + 7]), 0.f));
#pragma unroll
    for (int nb = 0; nb < NB; ++nb) {
      short8v b = bp[(kb * NB + nb) * 64 + lane];
      acc[nb] = __builtin_amdgcn_mfma_f32_16x16x32_bf16(a, b, acc[nb], 0, 0, 0);
    }
  }
  int r0 = (lane >> 4) * 4;
  int coll = lane & 15;
#pragma unroll
  for (int nb = 0; nb < NB; ++nb) {
    int col = nb * 16 + coll;
    float bv = bias[col];
#pragma unroll
    for (int r = 0; r < 4; ++r) {
      long long row = row0 + r0 + r;
      float v = acc[nb][r] + bv;
      if (OUT_BF16) ((unsigned short*)outp)[row * NOUT + col] = f2bf(v);
      else ((float*)outp)[row * NOUT + col] = v;
    }
  }
}

// ---- BN finalize + clear stats for the next layer ----
template<int D>
__global__ void bn_finalize_kernel(float* __restrict__ stats, const float* __restrict__ g,
                                   const float* __restrict__ be, float* scale, float* shift) {
  int f = threadIdx.x;  // 128 threads
  float s0 = 0.f, s1 = 0.f;
  if (f < D) { s0 = stats[f]; s1 = stats[D + f]; }
  __syncthreads();
  stats[f] = 0.f;
  stats[128 + f] = 0.f;
  if (f < D) {
    float mean = s0 * (1.0f / N_NODES);
    float var = s1 * (1.0f / N_NODES) - mean * mean;
    float rstd = rsqrtf(var + BN_EPS);
    float sc = g[f] * rstd;
    scale[f] = sc;
    shift[f] = be[f] - mean * sc;
  }
}

extern "C" void kernel_launch(void* const* d_in, const int* in_sizes, int n_in,
                              void* d_out, int out_size, void* d_ws, size_t ws_size,
                              hipStream_t stream) {
  const int N = N_NODES;
  const float* x = (const float*)d_in[0];
  const int* src[3] = {(const int*)d_in[1], (const int*)d_in[3], (const int*)d_in[5]};
  const int* dst[3] = {(const int*)d_in[2], (const int*)d_in[4], (const int*)d_in[6]};
  const int E[3] = {in_sizes[1], in_sizes[3], in_sizes[5]};
  const int E_tot = E[0] + E[1] + E[2];

  const float* w0[3] = {(const float*)d_in[7], (const float*)d_in[9], (const float*)d_in[11]};
  const float* b0[3] = {(const float*)d_in[8], (const float*)d_in[10], (const float*)d_in[12]};
  const float* bn0_g = (const float*)d_in[13];
  const float* bn0_b = (const float*)d_in[14];
  const float* fc0_w = (const float*)d_in[15];
  const float* fc0_b = (const float*)d_in[16];
  const float* w1[3] = {(const float*)d_in[17], (const float*)d_in[19], (const float*)d_in[21]};
  const float* b1[3] = {(const float*)d_in[18], (const float*)d_in[20], (const float*)d_in[22]};
  const float* bn1_g = (const float*)d_in[23];
  const float* bn1_b = (const float*)d_in[24];
  const float* fc1_w = (const float*)d_in[25];
  const float* fc1_b = (const float*)d_in[26];

  // ---- workspace layout (~92 MB) ----
  char* p = (char*)d_ws;
  auto alloc = [&](size_t bytes) { char* r = p; p += (bytes + 255) & ~255ULL; return r; };
  float* rs_out = (float*)alloc((size_t)3 * N * 4);
  float* rs_in = (float*)alloc((size_t)3 * N * 4);
  int* row_ptr = (int*)alloc((size_t)3 * (N + 1) * 4);
  int* bbaseS = (int*)alloc((size_t)3 * (NBKT + 1) * 4);
  int* bbaseD = (int*)alloc((size_t)3 * (NBKT + 1) * 4);
  unsigned int* es = (unsigned int*)alloc((size_t)E_tot * 4);
  unsigned short* wpk = (unsigned short*)alloc((size_t)(18432 + 36864 + 9216 + 16384) * 2);
  float* b0s = (float*)alloc(96 * 4);
  float* b1s = (float*)alloc(128 * 4);
  float* stats = (float*)alloc(256 * 4);
  float* scale = (float*)alloc(128 * 4);
  float* shift = (float*)alloc(128 * 4);
  unsigned short* aggC = (unsigned short*)alloc((size_t)N * 288 * 2);
  float* hsum = (float*)alloc((size_t)N * 128 * 4);            // hosts tmp/tmp8/Hists/xb early
  unsigned short* h1 = (unsigned short*)alloc((size_t)N * 96 * 2);

  unsigned short* B0p = wpk;                          // 192x96
  unsigned short* B1p = wpk + 18432;                  // 288x128
  unsigned short* fc0p = wpk + 18432 + 36864;         // 96x96
  unsigned short* fc1p = wpk + 18432 + 36864 + 9216;  // 128x128

  // transient aliases inside hsum region (all dead before gemm0 writes hsum)
  unsigned int* tmp = (unsigned int*)hsum;                             // [0, 8.19MB)
  unsigned char* tmp8 = (unsigned char*)hsum + ((size_t)85 << 20 >> 3);// 8.5MB..10.6MB
  int* HistS = (int*)((char*)hsum + ((size_t)11 << 20));               // 1.57MB @ 11MB
  int* HistD = (int*)((char*)hsum + ((size_t)13 << 20));               // 1.57MB @ 13MB
  unsigned short* xb = (unsigned short*)hsum;                          // 8.19MB (after tmp dead)

  // ---- CSR build: merged histograms, merged scatters, rsqrt folded in ----
  r1ab_kernel<<<3 * NBL, 256, 0, stream>>>(src[0], src[1], src[2], dst[0], dst[1], dst[2],
                                           E[0], E[1], E[2], HistS, HistD);
  r2ab_kernel<<<6, 256, 0, stream>>>(HistS, HistD, bbaseS, bbaseD);
  r3ab_kernel<<<3 * NBL, 256, 0, stream>>>(src[0], src[1], src[2], dst[0], dst[1], dst[2],
                                           E[0], E[1], E[2], HistS, HistD, tmp, tmp8);
  r4b_kernel<<<3 * NBKT, 256, 0, stream>>>(tmp8, bbaseS, E[0], E[1], E[2], rs_out);
  r4_kernel<<<3 * NBKT, 256, 0, stream>>>(tmp, bbaseD, E[0], E[1], E[2], rs_out,
                                          es, row_ptr, rs_in);

  // ---- one-shot prep: x->bf16 (xb overlays dead tmp), weight packs, biases, stats=0 ----
  prep_kernel<<<cdiv(XB_N + 18432 + 36864 + 9216 + 16384 + 96 + 128 + 256, 256), 256, 0, stream>>>(
      x, xb, w0[0], w0[1], w0[2], w1[0], w1[1], w1[2], fc0_w, fc1_w,
      b0[0], b0[1], b0[2], b1[0], b1[1], b1[2], B0p, B1p, fc0p, fc1p, b0s, b1s, stats);

  const int B = 256;

  // ---- layer 0: merged gather (bf16 x, D=64) -> aggC [N][192]; GEMM+stats; FC fused BN ----
  gather3_kernel<64, 192><<<cdiv((long long)3 * N * 64, B), B, 0, stream>>>(
      (const unsigned int*)xb, row_ptr, es, rs_in, (unsigned int*)aggC, E[0], E[0] + E[1]);
  gemm_kernel<192, 96, 0, 1><<<N / 64, B, 0, stream>>>(aggC, B0p, b0s, hsum, stats);
  bn_finalize_kernel<96><<<1, 128, 0, stream>>>(stats, bn0_g, bn0_b, scale, shift);
  fcgemm_kernel<96, 96, 1><<<N / 64, B, 0, stream>>>(hsum, fc0p, scale, shift, fc0_b, h1);

  // ---- layer 1: merged gather (bf16 h1, D=96) -> aggC [N][288]; GEMM+stats; FC fused BN ----
  gather3_kernel<96, 288><<<cdiv((long long)3 * N * 64, B), B, 0, stream>>>(
      (const unsigned int*)h1, row_ptr, es, rs_in, (unsigned int*)aggC, E[0], E[0] + E[1]);
  gemm_kernel<288, 128, 0, 1><<<N / 64, B, 0, stream>>>(aggC, B1p, b1s, hsum, stats);
  bn_finalize_kernel<128><<<1, 128, 0, stream>>>(stats, bn1_g, bn1_b, scale, shift);
  fcgemm_kernel<128, 128, 0><<<N / 64, B, 0, stream>>>(hsum, fc1p, scale, shift, fc1_b,
                                                       (float*)d_out);
}

// Round 12
// 392.698 us; speedup vs baseline: 1.8462x; 1.0281x over previous
//
#include <hip/hip_runtime.h>
#include <hip/hip_bf16.h>

#define N_NODES 64000
#define BN_EPS 1e-5f
#define NBL 512      // radix blocks per type
#define NBKT 250     // coarse buckets = N_NODES / 256

typedef __attribute__((ext_vector_type(8))) short short8v;   // 8 bf16 (4 VGPRs)
typedef __attribute__((ext_vector_type(4))) float f32x4;

static inline int cdiv(long long a, int b) { return (int)((a + b - 1) / b); }

__device__ inline float bf2f(unsigned int u) {
  union { unsigned int i; float f; } v; v.i = u << 16; return v.f;
}
__device__ inline unsigned short f2bf(float f) {
  __hip_bfloat16 h = __float2bfloat16(f);
  return *reinterpret_cast<unsigned short*>(&h);
}

// ================= atomic-free CSR build (two-level radix, merged) =================
__global__ void r1ab_kernel(const int* __restrict__ s0, const int* __restrict__ s1,
                            const int* __restrict__ s2, const int* __restrict__ d0,
                            const int* __restrict__ d1, const int* __restrict__ d2,
                            int E0, int E1, int E2,
                            int* __restrict__ HistS, int* __restrict__ HistD) {
  int t = blockIdx.x / NBL, blk = blockIdx.x - t * NBL;
  const int* src = t == 0 ? s0 : (t == 1 ? s1 : s2);
  const int* dst = t == 0 ? d0 : (t == 1 ? d1 : d2);
  int E = t == 0 ? E0 : (t == 1 ? E1 : E2);
  __shared__ int hs[256], hd[256];
  hs[threadIdx.x] = 0; hd[threadIdx.x] = 0;
  __syncthreads();
  int ch = (E + NBL - 1) / NBL;
  int lo = blk * ch, hi = min(lo + ch, E);
  for (int i = lo + threadIdx.x; i < hi; i += 256) {
    atomicAdd(&hs[src[i] >> 8], 1);
    atomicAdd(&hd[dst[i] >> 8], 1);
  }
  __syncthreads();
  HistS[(t * NBL + blk) * 256 + threadIdx.x] = hs[threadIdx.x];
  HistD[(t * NBL + blk) * 256 + threadIdx.x] = hd[threadIdx.x];
}

__global__ void r2ab_kernel(int* __restrict__ HistS, int* __restrict__ HistD,
                            int* __restrict__ bbaseS, int* __restrict__ bbaseD) {
  int side = blockIdx.x / 3;   // 0 = src, 1 = dst
  int t = blockIdx.x - side * 3;
  int bin = threadIdx.x;
  int* H = (side ? HistD : HistS) + (size_t)t * NBL * 256;
  int* bb = (side ? bbaseD : bbaseS) + t * (NBKT + 1);
  int total = 0;
  for (int blk = 0; blk < NBL; ++blk) total += H[blk * 256 + bin];
  __shared__ int s[256];
  s[bin] = total;
  __syncthreads();
  for (int o = 1; o < 256; o <<= 1) {
    int a = (bin >= o) ? s[bin - o] : 0;
    __syncthreads();
    s[bin] += a;
    __syncthreads();
  }
  int base = s[bin] - total;
  if (bin <= NBKT) bb[bin] = base;
  int run = base;
  for (int blk = 0; blk < NBL; ++blk) {
    int v = H[blk * 256 + bin];
    H[blk * 256 + bin] = run;
    run += v;
  }
}

__global__ void r3ab_kernel(const int* __restrict__ s0, const int* __restrict__ s1,
                            const int* __restrict__ s2, const int* __restrict__ d0,
                            const int* __restrict__ d1, const int* __restrict__ d2,
                            int E0, int E1, int E2, const int* __restrict__ HistS,
                            const int* __restrict__ HistD, unsigned int* __restrict__ tmp,
                            unsigned char* __restrict__ tmp8) {
  int t = blockIdx.x / NBL, blk = blockIdx.x - t * NBL;
  const int* src = t == 0 ? s0 : (t == 1 ? s1 : s2);
  const int* dst = t == 0 ? d0 : (t == 1 ? d1 : d2);
  int E = t == 0 ? E0 : (t == 1 ? E1 : E2);
  int teo = (t == 0 ? 0 : (t == 1 ? E0 : E0 + E1));
  unsigned int* tp = tmp + teo;
  unsigned char* t8 = tmp8 + teo;
  __shared__ int offS[256], offD[256];
  offS[threadIdx.x] = HistS[(t * NBL + blk) * 256 + threadIdx.x];
  offD[threadIdx.x] = HistD[(t * NBL + blk) * 256 + threadIdx.x];
  __syncthreads();
  int ch = (E + NBL - 1) / NBL;
  int lo = blk * ch, hi = min(lo + ch, E);
  for (int i = lo + threadIdx.x; i < hi; i += 256) {
    int s = src[i], d = dst[i];
    int q = atomicAdd(&offS[s >> 8], 1);
    t8[q] = (unsigned char)(s & 255);
    int p = atomicAdd(&offD[d >> 8], 1);
    tp[p] = ((unsigned)(d & 255) << 16) | (unsigned)s;
  }
}

__global__ void r4b_kernel(const unsigned char* __restrict__ tmp8,
                           const int* __restrict__ bbaseS, int E0, int E1, int E2,
                           float* __restrict__ rs_out) {
  int t = blockIdx.x / NBKT, b = blockIdx.x - t * NBKT;
  const int* bb = bbaseS + t * (NBKT + 1);
  const unsigned char* tp = tmp8 + (t == 0 ? 0 : (t == 1 ? E0 : E0 + E1));
  int lo = bb[b], hi = bb[b + 1];
  __shared__ int c[256];
  c[threadIdx.x] = 0;
  __syncthreads();
  for (int i = lo + threadIdx.x; i < hi; i += 256) atomicAdd(&c[tp[i]], 1);
  __syncthreads();
  rs_out[t * N_NODES + b * 256 + threadIdx.x] = rsqrtf(fmaxf((float)c[threadIdx.x], 1.0f));
}

__global__ void r4_kernel(const unsigned int* __restrict__ tmp,
                          const int* __restrict__ bbaseD, int E0, int E1, int E2,
                          const float* __restrict__ rs_out_base,
                          unsigned int* __restrict__ es, int* __restrict__ row_ptr,
                          float* __restrict__ rs_in) {
  int t = blockIdx.x / NBKT, b = blockIdx.x - t * NBKT;
  const int* bb = bbaseD + t * (NBKT + 1);
  int teo = (t == 0 ? 0 : (t == 1 ? E0 : E0 + E1));
  int E = t == 0 ? E0 : (t == 1 ? E1 : E2);
  const unsigned int* tp = tmp + teo;
  unsigned int* esp = es + teo;
  const float* ro = rs_out_base + t * N_NODES;
  int lo = bb[b], hi = bb[b + 1];
  __shared__ int c[256], s[256];
  c[threadIdx.x] = 0;
  __syncthreads();
  for (int i = lo + threadIdx.x; i < hi; i += 256) atomicAdd(&c[tp[i] >> 16], 1);
  __syncthreads();
  int v = c[threadIdx.x];
  s[threadIdx.x] = v;
  __syncthreads();
  for (int o = 1; o < 256; o <<= 1) {
    int a = (threadIdx.x >= o) ? s[threadIdx.x - o] : 0;
    __syncthreads();
    s[threadIdx.x] += a;
    __syncthreads();
  }
  int excl = s[threadIdx.x] - v;
  int node = b * 256 + threadIdx.x;
  rs_in[t * N_NODES + node] = rsqrtf(fmaxf((float)v, 1.0f));
  row_ptr[t * (N_NODES + 1) + node] = lo + excl;
  if (b == NBKT - 1 && threadIdx.x == 255) row_ptr[t * (N_NODES + 1) + N_NODES] = E;
  __syncthreads();
  s[threadIdx.x] = lo + excl;
  __syncthreads();
  for (int i = lo + threadIdx.x; i < hi; i += 256) {
    unsigned int w = tp[i];
    int p = atomicAdd(&s[w >> 16], 1);
    unsigned int sid = w & 0xFFFF;
    unsigned int rb = (unsigned int)f2bf(ro[sid]);
    esp[p] = (rb << 16) | sid;
  }
}

// ================= one-shot prep: x->bf16, weight packs, bias sums, stats zero ======
__device__ inline void pack_one(const float* __restrict__ W, unsigned short* __restrict__ Bp,
                                int idx, int NOUT, int k_off, int NB) {
  int kl = idx / NOUT, n = idx - kl * NOUT;
  int k = k_off + kl;
  int kb = k >> 5, nb = n >> 4;
  int lane = (((k >> 3) & 3) << 4) | (n & 15);
  int e = k & 7;
  Bp[(((kb * NB) + nb) * 64 + lane) * 8 + e] = f2bf(W[idx]);
}

#define XB_N (N_NODES * 16)

__global__ void prep_kernel(const float* __restrict__ x, unsigned short* __restrict__ xb,
                            const float* w00, const float* w01, const float* w02,
                            const float* w10, const float* w11, const float* w12,
                            const float* fc0w, const float* fc1w,
                            const float* b00, const float* b01, const float* b02,
                            const float* b10, const float* b11, const float* b12,
                            unsigned short* B0p, unsigned short* B1p,
                            unsigned short* fc0p, unsigned short* fc1p,
                            float* b0s, float* b1s, float* statsA, float* statsB) {
  int idx = blockIdx.x * blockDim.x + threadIdx.x;
  if (idx < XB_N) {
    float4 v = ((const float4*)x)[idx];
    ushort4 o;
    o.x = f2bf(v.x); o.y = f2bf(v.y); o.z = f2bf(v.z); o.w = f2bf(v.w);
    ((ushort4*)xb)[idx] = o;
    return;
  }
  idx -= XB_N;
  if (idx < 3 * 6144) {
    int e = idx / 6144;
    pack_one(e == 0 ? w00 : (e == 1 ? w01 : w02), B0p, idx - e * 6144, 96, e * 64, 6);
    return;
  }
  idx -= 18432;
  if (idx < 3 * 12288) {
    int e = idx / 12288;
    pack_one(e == 0 ? w10 : (e == 1 ? w11 : w12), B1p, idx - e * 12288, 128, e * 96, 8);
    return;
  }
  idx -= 36864;
  if (idx < 9216) { pack_one(fc0w, fc0p, idx, 96, 0, 6); return; }
  idx -= 9216;
  if (idx < 16384) { pack_one(fc1w, fc1p, idx, 128, 0, 8); return; }
  idx -= 16384;
  if (idx < 96) { b0s[idx] = b00[idx] + b01[idx] + b02[idx]; return; }
  idx -= 96;
  if (idx < 128) { b1s[idx] = b10[idx] + b11[idx] + b12[idx]; return; }
  idx -= 128;
  if (idx < 192) { statsA[idx] = 0.f; return; }
  idx -= 192;
  if (idx < 256) { statsB[idx] = 0.f; return; }
}

// ---- merged pull aggregation: 2 half-wave slots x ILP4 = 8 edges in flight ----
template<int D, int STR>
__global__ __launch_bounds__(256) void gather3_kernel(
    const unsigned int* __restrict__ hb32, const int* __restrict__ row_ptr_base,
    const unsigned int* __restrict__ es_base, const float* __restrict__ rs_in_base,
    unsigned int* __restrict__ out32, int E0, int E01) {
  constexpr int RW = D / 2;    // row width in uints
  constexpr int SW = STR / 2;  // output row stride in uints
  int gwid = (blockIdx.x * blockDim.x + threadIdx.x) >> 6;
  int lane = threadIdx.x & 63;
  if (gwid >= 3 * N_NODES) return;
  int t = (gwid >= N_NODES) + (gwid >= 2 * N_NODES);
  int node = gwid - t * N_NODES;
  int eoff = t == 0 ? 0 : (t == 1 ? E0 : E01);
  const int* row_ptr = row_ptr_base + t * (N_NODES + 1);
  const unsigned int* es = es_base + eoff;
  const float* rs_in = rs_in_base + t * N_NODES;

  int slot = lane >> 5, c = lane & 31;
  const bool xtra = (D == 96) && (c < 16);
  int lo = row_ptr[node], hi = row_ptr[node + 1];

  float aL0 = 0.f, aL1 = 0.f, aL2 = 0.f, aL3 = 0.f;
  float aH0 = 0.f, aH1 = 0.f, aH2 = 0.f, aH3 = 0.f;
  float bL0 = 0.f, bL1 = 0.f, bL2 = 0.f, bL3 = 0.f;
  float bH0 = 0.f, bH1 = 0.f, bH2 = 0.f, bH3 = 0.f;

  int e = lo + slot;
  for (; e + 6 < hi; e += 8) {
    unsigned int w0 = es[e], w1 = es[e + 2], w2 = es[e + 4], w3 = es[e + 6];
    int s0 = w0 & 0xFFFF, s1 = w1 & 0xFFFF, s2 = w2 & 0xFFFF, s3 = w3 & 0xFFFF;
    float r0 = bf2f(w0 >> 16), r1 = bf2f(w1 >> 16), r2 = bf2f(w2 >> 16), r3 = bf2f(w3 >> 16);
    unsigned int u0 = hb32[s0 * RW + c], u1 = hb32[s1 * RW + c];
    unsigned int u2 = hb32[s2 * RW + c], u3 = hb32[s3 * RW + c];
    aL0 += r0 * bf2f(u0 & 0xFFFF); aH0 += r0 * bf2f(u0 >> 16);
    aL1 += r1 * bf2f(u1 & 0xFFFF); aH1 += r1 * bf2f(u1 >> 16);
    aL2 += r2 * bf2f(u2 & 0xFFFF); aH2 += r2 * bf2f(u2 >> 16);
    aL3 += r3 * bf2f(u3 & 0xFFFF); aH3 += r3 * bf2f(u3 >> 16);
    if (D == 96) {
      if (xtra) {
        unsigned int v0 = hb32[s0 * RW + 32 + c], v1 = hb32[s1 * RW + 32 + c];
        unsigned int v2 = hb32[s2 * RW + 32 + c], v3 = hb32[s3 * RW + 32 + c];
        bL0 += r0 * bf2f(v0 & 0xFFFF); bH0 += r0 * bf2f(v0 >> 16);
        bL1 += r1 * bf2f(v1 & 0xFFFF); bH1 += r1 * bf2f(v1 >> 16);
        bL2 += r2 * bf2f(v2 & 0xFFFF); bH2 += r2 * bf2f(v2 >> 16);
        bL3 += r3 * bf2f(v3 & 0xFFFF); bH3 += r3 * bf2f(v3 >> 16);
      }
    }
  }
  for (; e < hi; e += 2) {
    unsigned int w = es[e];
    int s = w & 0xFFFF;
    float r = bf2f(w >> 16);
    unsigned int u = hb32[s * RW + c];
    aL0 += r * bf2f(u & 0xFFFF); aH0 += r * bf2f(u >> 16);
    if (D == 96) {
      if (xtra) {
        unsigned int v = hb32[s * RW + 32 + c];
        bL0 += r * bf2f(v & 0xFFFF); bH0 += r * bf2f(v >> 16);
      }
    }
  }

  float aL = (aL0 + aL1) + (aL2 + aL3);
  float aH = (aH0 + aH1) + (aH2 + aH3);
  aL += __shfl_xor(aL, 32);
  aH += __shfl_xor(aH, 32);
  float bL = 0.f, bH = 0.f;
  if (D == 96) {
    bL = (bL0 + bL1) + (bL2 + bL3);
    bH = (bH0 + bH1) + (bH2 + bH3);
    bL += __shfl_xor(bL, 32);
    bH += __shfl_xor(bH, 32);
  }
  if (slot == 0) {
    float ri = rs_in[node];
    unsigned int o = ((unsigned int)f2bf(aH * ri) << 16) | (unsigned int)f2bf(aL * ri);
    __builtin_nontemporal_store(o, &out32[(size_t)node * SW + t * RW + c]);
    if (D == 96) {
      if (xtra) {
        unsigned int o2 = ((unsigned int)f2bf(bH * ri) << 16) | (unsigned int)f2bf(bL * ri);
        __builtin_nontemporal_store(o2, &out32[(size_t)node * SW + t * RW + 32 + c]);
      }
    }
  }
}

// ---- MFMA GEMM, bf16 out, fused column-stats (sum, sumsq) epilogue ----
template<int K, int NOUT>
__global__ void gemm_kernel(const unsigned short* __restrict__ A,
                            const unsigned short* __restrict__ Bp,
                            const float* __restrict__ bias,
                            unsigned short* __restrict__ outp,
                            float* __restrict__ stats) {
  constexpr int NB = NOUT / 16;
  constexpr int KB = K / 32;
  __shared__ float ls[NOUT], lq[NOUT];
  for (int i = threadIdx.x; i < NOUT; i += blockDim.x) { ls[i] = 0.f; lq[i] = 0.f; }
  __syncthreads();
  int wave = (blockIdx.x * blockDim.x + threadIdx.x) >> 6;
  int lane = threadIdx.x & 63;
  int row0 = wave * 16;
  int arow = row0 + (lane & 15);
  int kgrp = lane >> 4;
  f32x4 acc[NB];
#pragma unroll
  for (int i = 0; i < NB; ++i) acc[i] = (f32x4){0.f, 0.f, 0.f, 0.f};
  const short8v* ap = (const short8v*)(A + (long long)arow * K + kgrp * 8);
  const short8v* bp = (const short8v*)Bp;
#pragma unroll
  for (int kb = 0; kb < KB; ++kb) {
    short8v a = ap[kb * 4];
#pragma unroll
    for (int nb = 0; nb < NB; ++nb) {
      short8v b = bp[(kb * NB + nb) * 64 + lane];
      acc[nb] = __builtin_amdgcn_mfma_f32_16x16x32_bf16(a, b, acc[nb], 0, 0, 0);
    }
  }
  int r0 = (lane >> 4) * 4;
  int coll = lane & 15;
#pragma unroll
  for (int nb = 0; nb < NB; ++nb) {
    int col = nb * 16 + coll;
    float bv = bias[col];
    float s = 0.f, q = 0.f;
#pragma unroll
    for (int r = 0; r < 4; ++r) {
      long long row = row0 + r0 + r;
      float v = acc[nb][r] + bv;
      outp[row * NOUT + col] = f2bf(v);
      s += v; q += v * v;
    }
    s += __shfl_xor(s, 16); q += __shfl_xor(q, 16);
    s += __shfl_xor(s, 32); q += __shfl_xor(q, 32);
    if (kgrp == 0) { atomicAdd(&ls[col], s); atomicAdd(&lq[col], q); }
  }
  __syncthreads();
  if (threadIdx.x < NOUT) {
    atomicAdd(&stats[threadIdx.x], ls[threadIdx.x]);
    atomicAdd(&stats[NOUT + threadIdx.x], lq[threadIdx.x]);
  }
}

// ---- FC GEMM: bf16 A, per-block BN finalize from stats, fused BN->ReLU->bf16 A-op ----
// OUT_BF16: 1 = bf16 out, 0 = f32 out (final layer)
template<int K, int NOUT, int OUT_BF16>
__global__ void fcgemm_kernel(const unsigned short* __restrict__ Af,
                              const unsigned short* __restrict__ Bp,
                              const float* __restrict__ stats, const float* __restrict__ g,
                              const float* __restrict__ be, const float* __restrict__ bias,
                              void* __restrict__ outp) {
  constexpr int NB = NOUT / 16;
  constexpr int KB = K / 32;
  __shared__ float sc[K], sh[K];
  if (threadIdx.x < K) {
    float mean = stats[threadIdx.x] * (1.0f / N_NODES);
    float var = stats[K + threadIdx.x] * (1.0f / N_NODES) - mean * mean;
    float rstd = rsqrtf(var + BN_EPS);
    float s = g[threadIdx.x] * rstd;
    sc[threadIdx.x] = s;
    sh[threadIdx.x] = be[threadIdx.x] - mean * s;
  }
  __syncthreads();
  int wave = (blockIdx.x * blockDim.x + threadIdx.x) >> 6;
  int lane = threadIdx.x & 63;
  int row0 = wave * 16;
  int arow = row0 + (lane & 15);
  int kgrp = lane >> 4;
  f32x4 acc[NB];
#pragma unroll
  for (int i = 0; i < NB; ++i) acc[i] = (f32x4){0.f, 0.f, 0.f, 0.f};
  const short8v* ap = (const short8v*)(Af + (long long)arow * K + kgrp * 8);
  const short8v* bp = (const short8v*)Bp;
#pragma unroll
  for (int kb = 0; kb < KB; ++kb) {
    short8v raw = ap[kb * 4];
    int kk = kb * 32 + kgrp * 8;
    short8v a;
#pragma unroll
    for (int j = 0; j < 8; ++j) {
      float v = bf2f((unsigned int)(unsigned short)raw[j]);
      a[j] = (short)f2bf(fmaxf(fmaf(v, sc[kk + j], sh[kk + j]), 0.f));
    }
#pragma unroll
    for (int nb = 0; nb < NB; ++nb) {
      short8v b = bp[(kb * NB + nb) * 64 + lane];
      acc[nb] = __builtin_amdgcn_mfma_f32_16x16x32_bf16(a, b, acc[nb], 0, 0, 0);
    }
  }
  int r0 = (lane >> 4) * 4;
  int coll = lane & 15;
#pragma unroll
  for (int nb = 0; nb < NB; ++nb) {
    int col = nb * 16 + coll;
    float bv = bias[col];
#pragma unroll
    for (int r = 0; r < 4; ++r) {
      long long row = row0 + r0 + r;
      float v = acc[nb][r] + bv;
      if (OUT_BF16) ((unsigned short*)outp)[row * NOUT + col] = f2bf(v);
      else ((float*)outp)[row * NOUT + col] = v;
    }
  }
}

extern "C" void kernel_launch(void* const* d_in, const int* in_sizes, int n_in,
                              void* d_out, int out_size, void* d_ws, size_t ws_size,
                              hipStream_t stream) {
  const int N = N_NODES;
  const float* x = (const float*)d_in[0];
  const int* src[3] = {(const int*)d_in[1], (const int*)d_in[3], (const int*)d_in[5]};
  const int* dst[3] = {(const int*)d_in[2], (const int*)d_in[4], (const int*)d_in[6]};
  const int E[3] = {in_sizes[1], in_sizes[3], in_sizes[5]};
  const int E_tot = E[0] + E[1] + E[2];

  const float* w0[3] = {(const float*)d_in[7], (const float*)d_in[9], (const float*)d_in[11]};
  const float* b0[3] = {(const float*)d_in[8], (const float*)d_in[10], (const float*)d_in[12]};
  const float* bn0_g = (const float*)d_in[13];
  const float* bn0_b = (const float*)d_in[14];
  const float* fc0_w = (const float*)d_in[15];
  const float* fc0_b = (const float*)d_in[16];
  const float* w1[3] = {(const float*)d_in[17], (const float*)d_in[19], (const float*)d_in[21]};
  const float* b1[3] = {(const float*)d_in[18], (const float*)d_in[20], (const float*)d_in[22]};
  const float* bn1_g = (const float*)d_in[23];
  const float* bn1_b = (const float*)d_in[24];
  const float* fc1_w = (const float*)d_in[25];
  const float* fc1_b = (const float*)d_in[26];

  // ---- workspace layout (~77 MB) ----
  char* p = (char*)d_ws;
  auto alloc = [&](size_t bytes) { char* r = p; p += (bytes + 255) & ~255ULL; return r; };
  float* rs_out = (float*)alloc((size_t)3 * N * 4);
  float* rs_in = (float*)alloc((size_t)3 * N * 4);
  int* row_ptr = (int*)alloc((size_t)3 * (N + 1) * 4);
  int* bbaseS = (int*)alloc((size_t)3 * (NBKT + 1) * 4);
  int* bbaseD = (int*)alloc((size_t)3 * (NBKT + 1) * 4);
  unsigned int* es = (unsigned int*)alloc((size_t)E_tot * 4);
  unsigned short* wpk = (unsigned short*)alloc((size_t)(18432 + 36864 + 9216 + 16384) * 2);
  float* b0s = (float*)alloc(96 * 4);
  float* b1s = (float*)alloc(128 * 4);
  float* statsA = (float*)alloc(192 * 4);
  float* statsB = (float*)alloc(256 * 4);
  unsigned short* aggC = (unsigned short*)alloc((size_t)N * 288 * 2);
  unsigned short* hsum = (unsigned short*)alloc((size_t)N * 128 * 2);  // bf16; hosts overlays early
  unsigned short* h1 = (unsigned short*)alloc((size_t)N * 96 * 2);

  unsigned short* B0p = wpk;                          // 192x96
  unsigned short* B1p = wpk + 18432;                  // 288x128
  unsigned short* fc0p = wpk + 18432 + 36864;         // 96x96
  unsigned short* fc1p = wpk + 18432 + 36864 + 9216;  // 128x128

  // transient aliases inside hsum region (16.38MB; all dead before gemm0 writes hsum)
  unsigned int* tmp = (unsigned int*)hsum;                             // [0, 8.19MB)
  unsigned char* tmp8 = (unsigned char*)hsum + ((size_t)85 << 20 >> 3);// 8.5MB..10.6MB
  int* HistS = (int*)((char*)hsum + ((size_t)11 << 20));               // 1.57MB @ 11MB
  int* HistD = (int*)((char*)hsum + ((size_t)13 << 20));               // 1.57MB @ 13MB
  unsigned short* xb = (unsigned short*)hsum;                          // 8.19MB (after tmp dead)

  // ---- CSR build: merged histograms, merged scatters, rsqrt folded in ----
  r1ab_kernel<<<3 * NBL, 256, 0, stream>>>(src[0], src[1], src[2], dst[0], dst[1], dst[2],
                                           E[0], E[1], E[2], HistS, HistD);
  r2ab_kernel<<<6, 256, 0, stream>>>(HistS, HistD, bbaseS, bbaseD);
  r3ab_kernel<<<3 * NBL, 256, 0, stream>>>(src[0], src[1], src[2], dst[0], dst[1], dst[2],
                                           E[0], E[1], E[2], HistS, HistD, tmp, tmp8);
  r4b_kernel<<<3 * NBKT, 256, 0, stream>>>(tmp8, bbaseS, E[0], E[1], E[2], rs_out);
  r4_kernel<<<3 * NBKT, 256, 0, stream>>>(tmp, bbaseD, E[0], E[1], E[2], rs_out,
                                          es, row_ptr, rs_in);

  // ---- one-shot prep ----
  prep_kernel<<<cdiv(XB_N + 18432 + 36864 + 9216 + 16384 + 96 + 128 + 192 + 256, 256), 256, 0,
                stream>>>(
      x, xb, w0[0], w0[1], w0[2], w1[0], w1[1], w1[2], fc0_w, fc1_w,
      b0[0], b0[1], b0[2], b1[0], b1[1], b1[2], B0p, B1p, fc0p, fc1p, b0s, b1s, statsA, statsB);

  const int B = 256;

  // ---- layer 0 ----
  gather3_kernel<64, 192><<<cdiv((long long)3 * N * 64, B), B, 0, stream>>>(
      (const unsigned int*)xb, row_ptr, es, rs_in, (unsigned int*)aggC, E[0], E[0] + E[1]);
  gemm_kernel<192, 96><<<N / 64, B, 0, stream>>>(aggC, B0p, b0s, hsum, statsA);
  fcgemm_kernel<96, 96, 1><<<N / 64, B, 0, stream>>>(hsum, fc0p, statsA, bn0_g, bn0_b,
                                                     fc0_b, h1);

  // ---- layer 1 ----
  gather3_kernel<96, 288><<<cdiv((long long)3 * N * 64, B), B, 0, stream>>>(
      (const unsigned int*)h1, row_ptr, es, rs_in, (unsigned int*)aggC, E[0], E[0] + E[1]);
  gemm_kernel<288, 128><<<N / 64, B, 0, stream>>>(aggC, B1p, b1s, hsum, statsB);
  fcgemm_kernel<128, 128, 0><<<N / 64, B, 0, stream>>>(hsum, fc1p, statsB, bn1_g, bn1_b,
                                                       fc1_b, (float*)d_out);
}